// Round 1
// baseline (3757.226 us; speedup 1.0000x reference)
//
#include <hip/hip_runtime.h>
#include <cstddef>

// ICTDIrrepsE3Conv — E(3) conv, fp32 baseline.
// Key simplifications vs reference:
//  - only paths (l1,0,l1) for l1=0,1,2 contribute (p = 0,3,9)
//  - CG[l,0,l][:,0,:] == identity  =>  contrib[w,o] = T_p[w] * Y_l[o]
//  - output = segment-mean over edge_dst of 144-dim edge features

__device__ __forceinline__ float silu(float x) {
    return x / (1.0f + __expf(-x));
}

__global__ __launch_bounds__(256) void node_mlp_kernel(
    const int* __restrict__ A, const float* __restrict__ emb_table,
    const float* __restrict__ w1, const float* __restrict__ b1,
    const float* __restrict__ w2, const float* __restrict__ b2,
    float* __restrict__ Ai, int n_nodes)
{
    int n = blockIdx.x * blockDim.x + threadIdx.x;
    if (n >= n_nodes) return;
    int a = A[n];
    float e[16];
    #pragma unroll
    for (int i = 0; i < 16; i++) e[i] = emb_table[a * 16 + i];
    float h[64];
    #pragma unroll
    for (int k = 0; k < 64; k++) {
        float acc = b1[k];
        #pragma unroll
        for (int i = 0; i < 16; i++) acc = fmaf(e[i], w1[i * 64 + k], acc);
        h[k] = silu(acc);
    }
    for (int j = 0; j < 8; j++) {
        float acc = b2[j];
        #pragma unroll
        for (int k = 0; k < 64; k++) acc = fmaf(h[k], w2[k * 8 + j], acc);
        Ai[(size_t)n * 8 + j] = acc;
    }
}

__global__ __launch_bounds__(256) void edge_kernel(
    const float* __restrict__ pos,
    const int* __restrict__ batch,
    const int* __restrict__ edge_src,
    const int* __restrict__ edge_dst,
    const float* __restrict__ edge_shifts,
    const float* __restrict__ cell,
    const float* __restrict__ fc_w1, const float* __restrict__ fc_b1,
    const float* __restrict__ fc_w2, const float* __restrict__ fc_b2,
    const float* __restrict__ fc_w3, const float* __restrict__ fc_b3,
    const float* __restrict__ tp_w,
    const float* __restrict__ Ai,
    float* __restrict__ out,
    float* __restrict__ counts,
    int n_edges)
{
    int e = blockIdx.x * blockDim.x + threadIdx.x;
    if (e >= n_edges) return;

    int src = edge_src[e];
    int dst = edge_dst[e];

    // shift vector: edge_shifts[e] @ cell[batch[src]]
    float sh0 = edge_shifts[3 * (size_t)e + 0];
    float sh1 = edge_shifts[3 * (size_t)e + 1];
    float sh2 = edge_shifts[3 * (size_t)e + 2];
    int g = batch[src];
    const float* C = cell + (size_t)g * 9;
    float shx = sh0 * C[0] + sh1 * C[3] + sh2 * C[6];
    float shy = sh0 * C[1] + sh1 * C[4] + sh2 * C[7];
    float shz = sh0 * C[2] + sh1 * C[5] + sh2 * C[8];

    float vx = pos[3 * (size_t)dst + 0] - pos[3 * (size_t)src + 0] + shx;
    float vy = pos[3 * (size_t)dst + 1] - pos[3 * (size_t)src + 1] + shy;
    float vz = pos[3 * (size_t)dst + 2] - pos[3 * (size_t)src + 2] + shz;

    float len = sqrtf(vx * vx + vy * vy + vz * vz);
    float invl = 1.0f / fmaxf(len, 1e-8f);
    float nx = vx * invl, ny = vy * invl, nz = vz * invl;

    // spherical harmonics
    const float s3  = 1.7320508075688772f;
    const float s15 = 3.872983346207417f;
    const float s5  = 2.23606797749979f;
    float Y1_[3] = { s3 * ny, s3 * nz, s3 * nx };
    float Y2_[5] = { s15 * nx * ny, s15 * ny * nz,
                     0.5f * s5 * (3.0f * nz * nz - 1.0f),
                     s15 * nx * nz, 0.5f * s15 * (nx * nx - ny * ny) };

    // radial basis: values[b] = (b+1)*5/17, step = 5/17
    // diff = (len - values[b]) / step = len*(17/5) - (b+1)
    float emb[16];
    const float inv_step = 17.0f / 5.0f;
    #pragma unroll
    for (int b = 0; b < 16; b++) {
        float d = len * inv_step - (float)(b + 1);
        emb[b] = __expf(-d * d) * 3.5714285714285716f; // 4/1.12
    }

    // radial MLP: 16 -> 64 (silu) -> 64 (silu) -> gates {0,3,9}
    float h1[64];
    #pragma unroll
    for (int k = 0; k < 64; k++) {
        float acc = fc_b1[k];
        #pragma unroll
        for (int b = 0; b < 16; b++) acc = fmaf(emb[b], fc_w1[b * 64 + k], acc);
        h1[k] = silu(acc);
    }
    float g0 = fc_b3[0], g3 = fc_b3[3], g9 = fc_b3[9];
    for (int k = 0; k < 64; k++) {
        float acc = fc_b2[k];
        #pragma unroll
        for (int j = 0; j < 64; j++) acc = fmaf(h1[j], fc_w2[j * 64 + k], acc);
        float h2 = silu(acc);
        g0 = fmaf(h2, fc_w3[k * 15 + 0], g0);
        g3 = fmaf(h2, fc_w3[k * 15 + 3], g3);
        g9 = fmaf(h2, fc_w3[k * 15 + 9], g9);
    }

    // tensor product: outer(f1, x2) contracted with tp_w[p], p in {0,3,9}
    float f1v[8], x2v[8];
    #pragma unroll
    for (int u = 0; u < 8; u++) f1v[u] = Ai[(size_t)src * 8 + u];
    #pragma unroll
    for (int v = 0; v < 8; v++) x2v[v] = Ai[(size_t)dst * 8 + v];
    float O[64];
    #pragma unroll
    for (int u = 0; u < 8; u++)
        #pragma unroll
        for (int v = 0; v < 8; v++) O[u * 8 + v] = f1v[u] * x2v[v];

    const float nrm = 0.125f; // 1/sqrt(MUL*MUL)
    float c0 = g0 * nrm, c1 = g3 * nrm, c2 = g9 * nrm;

    float* row = out + (size_t)dst * 144;
    for (int w = 0; w < 16; w++) {
        float a0 = 0.f, a1 = 0.f, a2 = 0.f;
        #pragma unroll
        for (int uv = 0; uv < 64; uv++) {
            float o = O[uv];
            a0 = fmaf(o, tp_w[(0   + uv) * 16 + w], a0);  // p=0  -> offset 0*64
            a1 = fmaf(o, tp_w[(192 + uv) * 16 + w], a1);  // p=3  -> offset 3*64
            a2 = fmaf(o, tp_w[(576 + uv) * 16 + w], a2);  // p=9  -> offset 9*64
        }
        a0 *= c0; a1 *= c1; a2 *= c2;
        // lo=0: cols [0,16);  lo=1: cols [16,64) idx w*3+i;  lo=2: cols [64,144) idx w*5+i
        atomicAdd(row + w, a0);
        #pragma unroll
        for (int i = 0; i < 3; i++) atomicAdd(row + 16 + w * 3 + i, a1 * Y1_[i]);
        #pragma unroll
        for (int i = 0; i < 5; i++) atomicAdd(row + 64 + w * 5 + i, a2 * Y2_[i]);
    }
    atomicAdd(counts + dst, 1.0f);
}

__global__ __launch_bounds__(256) void divide_kernel(
    float* __restrict__ out, const float* __restrict__ counts, int total)
{
    int i = blockIdx.x * blockDim.x + threadIdx.x;
    if (i >= total) return;
    int n = i / 144;
    out[i] = out[i] / fmaxf(counts[n], 1.0f);
}

extern "C" void kernel_launch(void* const* d_in, const int* in_sizes, int n_in,
                              void* d_out, int out_size, void* d_ws, size_t ws_size,
                              hipStream_t stream)
{
    const float* pos         = (const float*)d_in[0];
    const int*   A           = (const int*)d_in[1];
    const int*   batch       = (const int*)d_in[2];
    const int*   edge_src    = (const int*)d_in[3];
    const int*   edge_dst    = (const int*)d_in[4];
    const float* edge_shifts = (const float*)d_in[5];
    const float* cell        = (const float*)d_in[6];
    const float* emb_table   = (const float*)d_in[7];
    const float* mlp_w1      = (const float*)d_in[8];
    const float* mlp_b1      = (const float*)d_in[9];
    const float* mlp_w2      = (const float*)d_in[10];
    const float* mlp_b2      = (const float*)d_in[11];
    const float* fc_w1       = (const float*)d_in[12];
    const float* fc_b1       = (const float*)d_in[13];
    const float* fc_w2       = (const float*)d_in[14];
    const float* fc_b2       = (const float*)d_in[15];
    const float* fc_w3       = (const float*)d_in[16];
    const float* fc_b3       = (const float*)d_in[17];
    const float* tp_w        = (const float*)d_in[18];

    int n_nodes = in_sizes[1];
    int n_edges = in_sizes[3];

    float* Ai     = (float*)d_ws;                    // n_nodes*8 floats
    float* counts = Ai + (size_t)n_nodes * 8;        // n_nodes floats

    hipMemsetAsync(d_out, 0, (size_t)out_size * sizeof(float), stream);
    hipMemsetAsync(counts, 0, (size_t)n_nodes * sizeof(float), stream);

    node_mlp_kernel<<<(n_nodes + 255) / 256, 256, 0, stream>>>(
        A, emb_table, mlp_w1, mlp_b1, mlp_w2, mlp_b2, Ai, n_nodes);

    edge_kernel<<<(n_edges + 255) / 256, 256, 0, stream>>>(
        pos, batch, edge_src, edge_dst, edge_shifts, cell,
        fc_w1, fc_b1, fc_w2, fc_b2, fc_w3, fc_b3, tp_w,
        Ai, (float*)d_out, counts, n_edges);

    int total = n_nodes * 144;
    divide_kernel<<<(total + 255) / 256, 256, 0, stream>>>(
        (float*)d_out, counts, total);
}

// Round 2
// 417.582 us; speedup vs baseline: 8.9976x; 8.9976x over previous
//
#include <hip/hip_runtime.h>
#include <cstddef>

// ICTDIrrepsE3Conv — gather formulation (round 2).
//  - only paths (l1,0,l1), p in {0,3,9}, CG = identity
//  - scatter->gather: CSR by dst built on device; edge kernel writes an
//    11-float record into its dst bucket; wave-per-node gather kernel
//    does the tensor product with per-node precomputed B and writes the
//    mean directly (no output atomics).

__device__ __forceinline__ float silu(float x) {
    return x / (1.0f + __expf(-x));
}

__global__ __launch_bounds__(256) void node_mlp_kernel(
    const int* __restrict__ A, const float* __restrict__ emb_table,
    const float* __restrict__ w1, const float* __restrict__ b1,
    const float* __restrict__ w2, const float* __restrict__ b2,
    float* __restrict__ Ai, int n_nodes)
{
    int n = blockIdx.x * blockDim.x + threadIdx.x;
    if (n >= n_nodes) return;
    int a = A[n];
    float e[16];
    #pragma unroll
    for (int i = 0; i < 16; i++) e[i] = emb_table[a * 16 + i];
    float h[64];
    #pragma unroll
    for (int k = 0; k < 64; k++) {
        float acc = b1[k];
        #pragma unroll
        for (int i = 0; i < 16; i++) acc = fmaf(e[i], w1[i * 64 + k], acc);
        h[k] = silu(acc);
    }
    for (int j = 0; j < 8; j++) {
        float acc = b2[j];
        #pragma unroll
        for (int k = 0; k < 64; k++) acc = fmaf(h[k], w2[k * 8 + j], acc);
        Ai[(size_t)n * 8 + j] = acc;
    }
}

__global__ __launch_bounds__(256) void deg_kernel(
    const int* __restrict__ edge_dst, int* __restrict__ deg, int n_edges)
{
    int e = blockIdx.x * blockDim.x + threadIdx.x;
    if (e >= n_edges) return;
    atomicAdd(&deg[edge_dst[e]], 1);
}

// single-block exclusive scan over n (<=64K) ints -> starts and cursor
__global__ __launch_bounds__(1024) void scan_kernel(
    const int* __restrict__ deg, int* __restrict__ starts,
    int* __restrict__ cursor, int n)
{
    __shared__ int sdata[1024];
    __shared__ int s_carry;
    int tid = threadIdx.x;
    if (tid == 0) s_carry = 0;
    __syncthreads();
    int nchunks = (n + 1023) / 1024;
    for (int c = 0; c < nchunks; c++) {
        int i = c * 1024 + tid;
        int v = (i < n) ? deg[i] : 0;
        sdata[tid] = v;
        __syncthreads();
        #pragma unroll
        for (int off = 1; off < 1024; off <<= 1) {
            int t = (tid >= off) ? sdata[tid - off] : 0;
            __syncthreads();
            sdata[tid] += t;
            __syncthreads();
        }
        int incl = sdata[tid];
        int carry = s_carry;
        if (i < n) {
            int excl = carry + incl - v;
            starts[i] = excl;
            cursor[i] = excl;
        }
        __syncthreads();
        if (tid == 1023) s_carry = carry + incl;
        __syncthreads();
    }
}

// per-edge: radial MLP -> 3 gates; sph harmonics; write 12-float record
// into the dst bucket slot. record: [G0, GY1*3, GY2*5, src, pad, pad]
__global__ __launch_bounds__(256) void edge_kernel(
    const float* __restrict__ pos,
    const int* __restrict__ batch,
    const int* __restrict__ edge_src,
    const int* __restrict__ edge_dst,
    const float* __restrict__ edge_shifts,
    const float* __restrict__ cell,
    const float* __restrict__ fc_w1, const float* __restrict__ fc_b1,
    const float* __restrict__ fc_w2, const float* __restrict__ fc_b2,
    const float* __restrict__ fc_w3, const float* __restrict__ fc_b3,
    float* __restrict__ records,
    int* __restrict__ cursor,
    int n_edges)
{
    int e = blockIdx.x * blockDim.x + threadIdx.x;
    if (e >= n_edges) return;

    int src = edge_src[e];
    int dst = edge_dst[e];

    float sh0 = edge_shifts[3 * (size_t)e + 0];
    float sh1 = edge_shifts[3 * (size_t)e + 1];
    float sh2 = edge_shifts[3 * (size_t)e + 2];
    int g = batch[src];
    const float* C = cell + (size_t)g * 9;
    float shx = sh0 * C[0] + sh1 * C[3] + sh2 * C[6];
    float shy = sh0 * C[1] + sh1 * C[4] + sh2 * C[7];
    float shz = sh0 * C[2] + sh1 * C[5] + sh2 * C[8];

    float vx = pos[3 * (size_t)dst + 0] - pos[3 * (size_t)src + 0] + shx;
    float vy = pos[3 * (size_t)dst + 1] - pos[3 * (size_t)src + 1] + shy;
    float vz = pos[3 * (size_t)dst + 2] - pos[3 * (size_t)src + 2] + shz;

    float len = sqrtf(vx * vx + vy * vy + vz * vz);
    float invl = 1.0f / fmaxf(len, 1e-8f);
    float nx = vx * invl, ny = vy * invl, nz = vz * invl;

    const float s3  = 1.7320508075688772f;
    const float s15 = 3.872983346207417f;
    const float s5  = 2.23606797749979f;
    float Y1_[3] = { s3 * ny, s3 * nz, s3 * nx };
    float Y2_[5] = { s15 * nx * ny, s15 * ny * nz,
                     0.5f * s5 * (3.0f * nz * nz - 1.0f),
                     s15 * nx * nz, 0.5f * s15 * (nx * nx - ny * ny) };

    float emb[16];
    const float inv_step = 17.0f / 5.0f;
    #pragma unroll
    for (int b = 0; b < 16; b++) {
        float d = len * inv_step - (float)(b + 1);
        emb[b] = __expf(-d * d) * 3.5714285714285716f; // 4/1.12 * sqrt(16)
    }

    float h1[64];
    #pragma unroll
    for (int k = 0; k < 64; k++) {
        float acc = fc_b1[k];
        #pragma unroll
        for (int b = 0; b < 16; b++) acc = fmaf(emb[b], fc_w1[b * 64 + k], acc);
        h1[k] = silu(acc);
    }
    float g0 = fc_b3[0], g3 = fc_b3[3], g9 = fc_b3[9];
    for (int k = 0; k < 64; k++) {
        float acc = fc_b2[k];
        #pragma unroll
        for (int j = 0; j < 64; j++) acc = fmaf(h1[j], fc_w2[j * 64 + k], acc);
        float h2 = silu(acc);
        g0 = fmaf(h2, fc_w3[k * 15 + 0], g0);
        g3 = fmaf(h2, fc_w3[k * 15 + 3], g3);
        g9 = fmaf(h2, fc_w3[k * 15 + 9], g9);
    }

    const float nrm = 0.125f;
    g0 *= nrm; g3 *= nrm; g9 *= nrm;

    int pos_slot = atomicAdd(&cursor[dst], 1);
    float4* r = (float4*)(records + (size_t)pos_slot * 12);
    float4 r0 = { g0, g3 * Y1_[0], g3 * Y1_[1], g3 * Y1_[2] };
    float4 r1 = { g9 * Y2_[0], g9 * Y2_[1], g9 * Y2_[2], g9 * Y2_[3] };
    float4 r2 = { g9 * Y2_[4], __int_as_float(src), 0.0f, 0.0f };
    r[0] = r0; r[1] = r1; r[2] = r2;
}

// one wave per node; lane owns output components {lane, lane+64, lane+128<144}
__global__ __launch_bounds__(256) void gather_kernel(
    const float* __restrict__ records,
    const int* __restrict__ starts,
    const int* __restrict__ deg,
    const float* __restrict__ Ai,
    const float* __restrict__ tp_w,
    float* __restrict__ out, int n_nodes)
{
    int lane = threadIdx.x & 63;
    int node = blockIdx.x * 4 + (threadIdx.x >> 6);
    if (node >= n_nodes) return;

    int start = starts[node];
    int d = deg[node];

    float x2[8];
    #pragma unroll
    for (int v = 0; v < 8; v++) x2[v] = Ai[(size_t)node * 8 + v];

    // component setup (static per lane)
    int comps[3] = { lane, lane + 64, lane + 128 };
    int goff[3];
    float B[3][8];
    #pragma unroll
    for (int k = 0; k < 3; k++) {
        int c = comps[k];
        int p, w;
        if (c < 16)       { p = 0; w = c;                goff[k] = 0; }
        else if (c < 64)  { int t = c - 16; p = 3; w = t / 3; goff[k] = 1 + (t - 3 * (t / 3)); }
        else if (c < 144) { int t = c - 64; p = 9; w = t / 5; goff[k] = 4 + (t - 5 * (t / 5)); }
        else              { p = 0; w = 0; goff[k] = 0; } // inactive lanes>=16, k=2
        #pragma unroll
        for (int u = 0; u < 8; u++) {
            float acc = 0.0f;
            #pragma unroll
            for (int v = 0; v < 8; v++)
                acc = fmaf(x2[v], tp_w[(((size_t)p * 8 + u) * 8 + v) * 16 + w], acc);
            B[k][u] = acc;
        }
    }

    float acc0 = 0.0f, acc1 = 0.0f, acc2 = 0.0f;
    for (int j = 0; j < d; j++) {
        const float* rec = records + (size_t)(start + j) * 12;
        int src = __float_as_int(rec[9]);
        float G0v = rec[goff[0]];
        float G1v = rec[goff[1]];
        float G2v = rec[goff[2]];
        float a0 = 0.f, a1 = 0.f, a2 = 0.f;
        #pragma unroll
        for (int u = 0; u < 8; u++) {
            float f1 = Ai[(size_t)src * 8 + u];
            a0 = fmaf(f1, B[0][u], a0);
            a1 = fmaf(f1, B[1][u], a1);
            a2 = fmaf(f1, B[2][u], a2);
        }
        acc0 = fmaf(G0v, a0, acc0);
        acc1 = fmaf(G1v, a1, acc1);
        acc2 = fmaf(G2v, a2, acc2);
    }

    float invd = 1.0f / fmaxf((float)d, 1.0f);
    float* row = out + (size_t)node * 144;
    row[comps[0]] = acc0 * invd;
    row[comps[1]] = acc1 * invd;
    if (lane < 16) row[comps[2]] = acc2 * invd;
}

extern "C" void kernel_launch(void* const* d_in, const int* in_sizes, int n_in,
                              void* d_out, int out_size, void* d_ws, size_t ws_size,
                              hipStream_t stream)
{
    const float* pos         = (const float*)d_in[0];
    const int*   A           = (const int*)d_in[1];
    const int*   batch       = (const int*)d_in[2];
    const int*   edge_src    = (const int*)d_in[3];
    const int*   edge_dst    = (const int*)d_in[4];
    const float* edge_shifts = (const float*)d_in[5];
    const float* cell        = (const float*)d_in[6];
    const float* emb_table   = (const float*)d_in[7];
    const float* mlp_w1      = (const float*)d_in[8];
    const float* mlp_b1      = (const float*)d_in[9];
    const float* mlp_w2      = (const float*)d_in[10];
    const float* mlp_b2      = (const float*)d_in[11];
    const float* fc_w1       = (const float*)d_in[12];
    const float* fc_b1       = (const float*)d_in[13];
    const float* fc_w2       = (const float*)d_in[14];
    const float* fc_b2       = (const float*)d_in[15];
    const float* fc_w3       = (const float*)d_in[16];
    const float* fc_b3       = (const float*)d_in[17];
    const float* tp_w        = (const float*)d_in[18];

    int n_nodes = in_sizes[1];
    int n_edges = in_sizes[3];

    // ws layout
    float* Ai      = (float*)d_ws;                               // n_nodes*8 f
    int*   deg     = (int*)(Ai + (size_t)n_nodes * 8);           // n_nodes
    int*   starts  = deg + n_nodes;                              // n_nodes
    int*   cursor  = starts + n_nodes;                           // n_nodes
    float* records = (float*)(cursor + n_nodes);                 // n_edges*12 f

    hipMemsetAsync(deg, 0, (size_t)n_nodes * sizeof(int), stream);

    node_mlp_kernel<<<(n_nodes + 255) / 256, 256, 0, stream>>>(
        A, emb_table, mlp_w1, mlp_b1, mlp_w2, mlp_b2, Ai, n_nodes);

    deg_kernel<<<(n_edges + 255) / 256, 256, 0, stream>>>(edge_dst, deg, n_edges);

    scan_kernel<<<1, 1024, 0, stream>>>(deg, starts, cursor, n_nodes);

    edge_kernel<<<(n_edges + 255) / 256, 256, 0, stream>>>(
        pos, batch, edge_src, edge_dst, edge_shifts, cell,
        fc_w1, fc_b1, fc_w2, fc_b2, fc_w3, fc_b3,
        records, cursor, n_edges);

    gather_kernel<<<(n_nodes + 3) / 4, 256, 0, stream>>>(
        records, starts, deg, Ai, tp_w, (float*)d_out, n_nodes);
}

// Round 3
// 362.988 us; speedup vs baseline: 10.3508x; 1.1504x over previous
//
#include <hip/hip_runtime.h>
#include <cstddef>

// ICTDIrrepsE3Conv — round 3.
//  - only paths (l1,0,l1), p in {0,3,9}, CG = identity
//  - CSR gather with M-factorization:
//      M[i'][u]   = sum_j rec_j[i'] * f1_j[u]          (per-edge: 1 FMA/lane)
//      out[p,w,i] = sum_u B_p[u][w] * M[i'(p,i)][u]    (per-node finish via LDS)
//      B_p[u][w]  = sum_v x2[v] * tp_w[p][u][v][w]     (tp_w 3 paths staged in LDS)
//  - fast chunked single-block scan
//  - edge MLP: h1[64] register-resident, layer2 in 4x16 accumulator chunks

__device__ __forceinline__ float silu(float x) {
    return x / (1.0f + __expf(-x));
}

__global__ __launch_bounds__(256) void node_mlp_kernel(
    const int* __restrict__ A, const float* __restrict__ emb_table,
    const float* __restrict__ w1, const float* __restrict__ b1,
    const float* __restrict__ w2, const float* __restrict__ b2,
    float* __restrict__ Ai, int n_nodes)
{
    int n = blockIdx.x * blockDim.x + threadIdx.x;
    if (n >= n_nodes) return;
    int a = A[n];
    float e[16];
    #pragma unroll
    for (int i = 0; i < 16; i++) e[i] = emb_table[a * 16 + i];
    float h[64];
    #pragma unroll
    for (int k = 0; k < 64; k++) {
        float acc = b1[k];
        #pragma unroll
        for (int i = 0; i < 16; i++) acc = fmaf(e[i], w1[i * 64 + k], acc);
        h[k] = silu(acc);
    }
    #pragma unroll
    for (int j = 0; j < 8; j++) {
        float acc = b2[j];
        #pragma unroll
        for (int k = 0; k < 64; k++) acc = fmaf(h[k], w2[k * 8 + j], acc);
        Ai[(size_t)n * 8 + j] = acc;
    }
}

__global__ __launch_bounds__(256) void deg_kernel(
    const int* __restrict__ edge_dst, int* __restrict__ deg, int n_edges)
{
    int e = blockIdx.x * blockDim.x + threadIdx.x;
    if (e >= n_edges) return;
    atomicAdd(&deg[edge_dst[e]], 1);
}

// single-block chunked exclusive scan: thread t sums its chunk, block-scan of
// 1024 totals, then serial prefix write-back. ~2 passes over deg.
__global__ __launch_bounds__(1024) void scan_kernel(
    const int* __restrict__ deg, int* __restrict__ starts,
    int* __restrict__ cursor, int n)
{
    __shared__ int s_tot[1024];
    int tid = threadIdx.x;
    int ch = (n + 1023) >> 10;
    int lo = tid * ch;
    int hi = min(n, lo + ch);
    int s = 0;
    for (int i = lo; i < hi; i++) s += deg[i];
    s_tot[tid] = s;
    __syncthreads();
    #pragma unroll
    for (int off = 1; off < 1024; off <<= 1) {
        int v = (tid >= off) ? s_tot[tid - off] : 0;
        __syncthreads();
        s_tot[tid] += v;
        __syncthreads();
    }
    int base = s_tot[tid] - s; // exclusive offset of this chunk
    for (int i = lo; i < hi; i++) {
        starts[i] = base;
        cursor[i] = base;
        base += deg[i];
    }
}

// per-edge: radial MLP -> 3 gates; sph harmonics; write 12-float record
// into the dst bucket slot. record: [G0, G1*Y1[0..2], G2*Y2[0..4], src, pad, pad]
__global__ void edge_kernel(
    const float* __restrict__ pos,
    const int* __restrict__ batch,
    const int* __restrict__ edge_src,
    const int* __restrict__ edge_dst,
    const float* __restrict__ edge_shifts,
    const float* __restrict__ cell,
    const float* __restrict__ fc_w1, const float* __restrict__ fc_b1,
    const float* __restrict__ fc_w2, const float* __restrict__ fc_b2,
    const float* __restrict__ fc_w3, const float* __restrict__ fc_b3,
    float* __restrict__ records,
    int* __restrict__ cursor,
    int n_edges)
{
    int e = blockIdx.x * blockDim.x + threadIdx.x;
    if (e >= n_edges) return;

    int src = edge_src[e];
    int dst = edge_dst[e];

    float sh0 = edge_shifts[3 * (size_t)e + 0];
    float sh1 = edge_shifts[3 * (size_t)e + 1];
    float sh2 = edge_shifts[3 * (size_t)e + 2];
    int g = batch[src];
    const float* C = cell + (size_t)g * 9;
    float shx = sh0 * C[0] + sh1 * C[3] + sh2 * C[6];
    float shy = sh0 * C[1] + sh1 * C[4] + sh2 * C[7];
    float shz = sh0 * C[2] + sh1 * C[5] + sh2 * C[8];

    float vx = pos[3 * (size_t)dst + 0] - pos[3 * (size_t)src + 0] + shx;
    float vy = pos[3 * (size_t)dst + 1] - pos[3 * (size_t)src + 1] + shy;
    float vz = pos[3 * (size_t)dst + 2] - pos[3 * (size_t)src + 2] + shz;

    float len = sqrtf(vx * vx + vy * vy + vz * vz);
    float invl = 1.0f / fmaxf(len, 1e-8f);
    float nx = vx * invl, ny = vy * invl, nz = vz * invl;

    const float s3  = 1.7320508075688772f;
    const float s15 = 3.872983346207417f;
    const float s5  = 2.23606797749979f;
    float Y1_[3] = { s3 * ny, s3 * nz, s3 * nx };
    float Y2_[5] = { s15 * nx * ny, s15 * ny * nz,
                     0.5f * s5 * (3.0f * nz * nz - 1.0f),
                     s15 * nx * nz, 0.5f * s15 * (nx * nx - ny * ny) };

    float emb[16];
    const float inv_step = 17.0f / 5.0f;
    #pragma unroll
    for (int b = 0; b < 16; b++) {
        float d = len * inv_step - (float)(b + 1);
        emb[b] = __expf(-d * d) * 3.5714285714285716f; // 4/1.12
    }

    float h1[64];
    #pragma unroll
    for (int k = 0; k < 64; k++) {
        float acc = fc_b1[k];
        #pragma unroll
        for (int b = 0; b < 16; b++) acc = fmaf(emb[b], fc_w1[b * 64 + k], acc);
        h1[k] = silu(acc);
    }

    float g0 = fc_b3[0], g3 = fc_b3[3], g9 = fc_b3[9];
    #pragma unroll
    for (int c = 0; c < 4; c++) {
        float acc[16];
        #pragma unroll
        for (int t = 0; t < 16; t++) acc[t] = fc_b2[c * 16 + t];
        #pragma unroll
        for (int j = 0; j < 64; j++) {
            float hj = h1[j];
            #pragma unroll
            for (int t = 0; t < 16; t++)
                acc[t] = fmaf(hj, fc_w2[j * 64 + c * 16 + t], acc[t]);
        }
        #pragma unroll
        for (int t = 0; t < 16; t++) {
            float h2 = silu(acc[t]);
            int k = c * 16 + t;
            g0 = fmaf(h2, fc_w3[k * 15 + 0], g0);
            g3 = fmaf(h2, fc_w3[k * 15 + 3], g3);
            g9 = fmaf(h2, fc_w3[k * 15 + 9], g9);
        }
    }

    const float nrm = 0.125f;
    g0 *= nrm; g3 *= nrm; g9 *= nrm;

    int pos_slot = atomicAdd(&cursor[dst], 1);
    float4* r = (float4*)(records + (size_t)pos_slot * 12);
    float4 r0 = { g0, g3 * Y1_[0], g3 * Y1_[1], g3 * Y1_[2] };
    float4 r1 = { g9 * Y2_[0], g9 * Y2_[1], g9 * Y2_[2], g9 * Y2_[3] };
    float4 r2 = { g9 * Y2_[4], __int_as_float(src), 0.0f, 0.0f };
    r[0] = r0; r[1] = r1; r[2] = r2;
}

// one wave per node. Phase 1: lane (iq=lane>>3, u=lane&7) accumulates
// M[iq][u] (+ M[8][u] via all-lane redundant m8). Phase 2: B = x2 . tp_w
// from LDS-staged tp_w. Phase 3: 144 contractions of length 8 via LDS.
__global__ __launch_bounds__(256) void gather_kernel(
    const float* __restrict__ records,
    const int* __restrict__ starts,
    const int* __restrict__ deg,
    const float* __restrict__ Ai,
    const float* __restrict__ tp_w,
    float* __restrict__ out, int n_nodes)
{
    __shared__ float s_tp[3072];     // 3 paths: [pp][u][v][w]
    __shared__ float s_B[4][384];    // per wave: [pp*128 + u*16 + w]
    __shared__ float s_M[4][80];     // per wave: [i'*8 + u], i' in 0..8

    int tid = threadIdx.x;
    for (int t = tid; t < 3072; t += 256) {
        int pp = t >> 10;
        int P = (pp == 0) ? 0 : (pp == 1) ? 3 : 9;
        s_tp[t] = tp_w[P * 1024 + (t & 1023)];
    }
    __syncthreads();

    int wv = tid >> 6;
    int lane = tid & 63;
    int node = blockIdx.x * 4 + wv;
    if (node >= n_nodes) return;

    int start = starts[node];
    int d = deg[node];
    int iq = lane >> 3, u = lane & 7;

    float x2[8];
    #pragma unroll
    for (int v = 0; v < 8; v++) x2[v] = Ai[(size_t)node * 8 + v];

    // phase 1: M accumulation, unrolled by 2 for ILP
    float m = 0.0f, m8 = 0.0f;
    const float* recs = records + (size_t)start * 12;
    int j = 0;
    for (; j + 2 <= d; j += 2) {
        const float* r0 = recs + (size_t)j * 12;
        const float* r1 = r0 + 12;
        float gv0 = r0[iq];
        float gv1 = r1[iq];
        float g80 = r0[8];
        float g81 = r1[8];
        int s0 = __float_as_int(r0[9]);
        int s1 = __float_as_int(r1[9]);
        float f0 = Ai[(size_t)s0 * 8 + u];
        float f1v = Ai[(size_t)s1 * 8 + u];
        m  = fmaf(gv0, f0, m);
        m8 = fmaf(g80, f0, m8);
        m  = fmaf(gv1, f1v, m);
        m8 = fmaf(g81, f1v, m8);
    }
    for (; j < d; j++) {
        const float* r0 = recs + (size_t)j * 12;
        float gv0 = r0[iq];
        float g80 = r0[8];
        int s0 = __float_as_int(r0[9]);
        float f0 = Ai[(size_t)s0 * 8 + u];
        m  = fmaf(gv0, f0, m);
        m8 = fmaf(g80, f0, m8);
    }
    s_M[wv][iq * 8 + u] = m;
    if (lane < 8) s_M[wv][64 + u] = m8;

    // phase 2: B_pp[u][w], 6 values per lane
    #pragma unroll
    for (int s = 0; s < 6; s++) {
        int t = lane + 64 * s;            // 0..383
        int pp = t >> 7;
        int ub = (t >> 4) & 7;
        int wb = t & 15;
        float acc = 0.0f;
        #pragma unroll
        for (int v = 0; v < 8; v++)
            acc = fmaf(x2[v], s_tp[((pp * 8 + ub) * 8 + v) * 16 + wb], acc);
        s_B[wv][t] = acc;
    }

    // phase 3: contractions (intra-wave LDS deps handled by waitcnt)
    float invd = 1.0f / fmaxf((float)d, 1.0f);
    float* row = out + (size_t)node * 144;
    {
        int c = lane;
        int pp, w, ip;
        if (c < 16) { pp = 0; w = c; ip = 0; }
        else { int t = c - 16; pp = 1; w = t / 3; ip = 1 + (t - 3 * (t / 3)); }
        float acc = 0.0f;
        #pragma unroll
        for (int uu = 0; uu < 8; uu++)
            acc = fmaf(s_B[wv][pp * 128 + uu * 16 + w], s_M[wv][ip * 8 + uu], acc);
        row[c] = acc * invd;
    }
    {
        int t = lane;                      // c = 64 + lane
        int w = t / 5; int i = t - 5 * w;
        float acc = 0.0f;
        #pragma unroll
        for (int uu = 0; uu < 8; uu++)
            acc = fmaf(s_B[wv][256 + uu * 16 + w], s_M[wv][(4 + i) * 8 + uu], acc);
        row[64 + lane] = acc * invd;
    }
    if (lane < 16) {
        int t = 64 + lane;                 // c = 128 + lane
        int w = t / 5; int i = t - 5 * w;
        float acc = 0.0f;
        #pragma unroll
        for (int uu = 0; uu < 8; uu++)
            acc = fmaf(s_B[wv][256 + uu * 16 + w], s_M[wv][(4 + i) * 8 + uu], acc);
        row[128 + lane] = acc * invd;
    }
}

extern "C" void kernel_launch(void* const* d_in, const int* in_sizes, int n_in,
                              void* d_out, int out_size, void* d_ws, size_t ws_size,
                              hipStream_t stream)
{
    const float* pos         = (const float*)d_in[0];
    const int*   A           = (const int*)d_in[1];
    const int*   batch       = (const int*)d_in[2];
    const int*   edge_src    = (const int*)d_in[3];
    const int*   edge_dst    = (const int*)d_in[4];
    const float* edge_shifts = (const float*)d_in[5];
    const float* cell        = (const float*)d_in[6];
    const float* emb_table   = (const float*)d_in[7];
    const float* mlp_w1      = (const float*)d_in[8];
    const float* mlp_b1      = (const float*)d_in[9];
    const float* mlp_w2      = (const float*)d_in[10];
    const float* mlp_b2      = (const float*)d_in[11];
    const float* fc_w1       = (const float*)d_in[12];
    const float* fc_b1       = (const float*)d_in[13];
    const float* fc_w2       = (const float*)d_in[14];
    const float* fc_b2       = (const float*)d_in[15];
    const float* fc_w3       = (const float*)d_in[16];
    const float* fc_b3       = (const float*)d_in[17];
    const float* tp_w        = (const float*)d_in[18];

    int n_nodes = in_sizes[1];
    int n_edges = in_sizes[3];

    float* Ai      = (float*)d_ws;                               // n_nodes*8 f
    int*   deg     = (int*)(Ai + (size_t)n_nodes * 8);           // n_nodes
    int*   starts  = deg + n_nodes;                              // n_nodes
    int*   cursor  = starts + n_nodes;                           // n_nodes
    float* records = (float*)(cursor + n_nodes);                 // n_edges*12 f

    hipMemsetAsync(deg, 0, (size_t)n_nodes * sizeof(int), stream);

    node_mlp_kernel<<<(n_nodes + 255) / 256, 256, 0, stream>>>(
        A, emb_table, mlp_w1, mlp_b1, mlp_w2, mlp_b2, Ai, n_nodes);

    deg_kernel<<<(n_edges + 255) / 256, 256, 0, stream>>>(edge_dst, deg, n_edges);

    scan_kernel<<<1, 1024, 0, stream>>>(deg, starts, cursor, n_nodes);

    edge_kernel<<<(n_edges + 255) / 256, 256, 0, stream>>>(
        pos, batch, edge_src, edge_dst, edge_shifts, cell,
        fc_w1, fc_b1, fc_w2, fc_b2, fc_w3, fc_b3,
        records, cursor, n_edges);

    gather_kernel<<<(n_nodes + 3) / 4, 256, 0, stream>>>(
        records, starts, deg, Ai, tp_w, (float*)d_out, n_nodes);
}

// Round 4
// 259.924 us; speedup vs baseline: 14.4551x; 1.3965x over previous
//
#include <hip/hip_runtime.h>
#include <cstddef>

// ICTDIrrepsE3Conv — round 4.
//  - gates = f(edge_length) only -> 8192-entry lerp table (kills the
//    per-edge 20KB weight stream that caused 10.4 GB FETCH)
//  - Ai has only MAX_ATOM=10 distinct rows -> per-block LDS compute + copy
//  - edge record carries f1 = Ai[src] (17 floats) -> gather phase-1 is a
//    pure streaming reduce, no dependent load chain

#define TBL_N 8192
#define TBL_SCALE 1024.0f   // TBL_N / 8.0 range

__device__ __forceinline__ float silu(float x) {
    return x / (1.0f + __expf(-x));
}

// ---- gates lookup table build: one thread per length sample ----
__global__ __launch_bounds__(256) void table_kernel(
    const float* __restrict__ fc_w1, const float* __restrict__ fc_b1,
    const float* __restrict__ fc_w2, const float* __restrict__ fc_b2,
    const float* __restrict__ fc_w3, const float* __restrict__ fc_b3,
    float4* __restrict__ table)
{
    int i = blockIdx.x * blockDim.x + threadIdx.x;
    if (i >= TBL_N) return;
    float len = (float)i * (1.0f / TBL_SCALE);

    float emb[16];
    const float inv_step = 17.0f / 5.0f;
    #pragma unroll
    for (int b = 0; b < 16; b++) {
        float d = len * inv_step - (float)(b + 1);
        emb[b] = __expf(-d * d) * 3.5714285714285716f; // 4/1.12
    }
    float h1[64];
    #pragma unroll
    for (int k = 0; k < 64; k++) {
        float acc = fc_b1[k];
        #pragma unroll
        for (int b = 0; b < 16; b++) acc = fmaf(emb[b], fc_w1[b * 64 + k], acc);
        h1[k] = silu(acc);
    }
    float g0 = fc_b3[0], g3 = fc_b3[3], g9 = fc_b3[9];
    for (int k = 0; k < 64; k++) {
        float acc = fc_b2[k];
        #pragma unroll
        for (int j = 0; j < 64; j++) acc = fmaf(h1[j], fc_w2[j * 64 + k], acc);
        float h2 = silu(acc);
        g0 = fmaf(h2, fc_w3[k * 15 + 0], g0);
        g3 = fmaf(h2, fc_w3[k * 15 + 3], g3);
        g9 = fmaf(h2, fc_w3[k * 15 + 9], g9);
    }
    table[i] = make_float4(g0 * 0.125f, g3 * 0.125f, g9 * 0.125f, 0.0f);
}

// ---- Ai: 10 distinct rows computed redundantly per block, then copy ----
__global__ __launch_bounds__(256) void ai_kernel(
    const int* __restrict__ A, const float* __restrict__ emb_table,
    const float* __restrict__ w1, const float* __restrict__ b1,
    const float* __restrict__ w2, const float* __restrict__ b2,
    float* __restrict__ Ai, int n_nodes, int n_atom)
{
    __shared__ float s_rows[16 * 8];
    int tid = threadIdx.x;
    if (tid < n_atom * 8) {
        int a = tid >> 3, j = tid & 7;
        float e[16];
        #pragma unroll
        for (int i = 0; i < 16; i++) e[i] = emb_table[a * 16 + i];
        float acc_j = b2[j];
        for (int k = 0; k < 64; k++) {
            float acc = b1[k];
            #pragma unroll
            for (int i = 0; i < 16; i++) acc = fmaf(e[i], w1[i * 64 + k], acc);
            acc_j = fmaf(silu(acc), w2[k * 8 + j], acc_j);
        }
        s_rows[tid] = acc_j;
    }
    __syncthreads();
    int n = blockIdx.x * blockDim.x + tid;
    if (n >= n_nodes) return;
    int a = A[n];
    #pragma unroll
    for (int j = 0; j < 8; j++) Ai[(size_t)n * 8 + j] = s_rows[a * 8 + j];
}

__global__ __launch_bounds__(256) void deg_kernel(
    const int* __restrict__ edge_dst, int* __restrict__ deg, int n_edges)
{
    int e = blockIdx.x * blockDim.x + threadIdx.x;
    if (e >= n_edges) return;
    atomicAdd(&deg[edge_dst[e]], 1);
}

__global__ __launch_bounds__(1024) void scan_kernel(
    const int* __restrict__ deg, int* __restrict__ starts,
    int* __restrict__ cursor, int n)
{
    __shared__ int s_tot[1024];
    int tid = threadIdx.x;
    int ch = (n + 1023) >> 10;
    int lo = tid * ch;
    int hi = min(n, lo + ch);
    int s = 0;
    for (int i = lo; i < hi; i++) s += deg[i];
    s_tot[tid] = s;
    __syncthreads();
    #pragma unroll
    for (int off = 1; off < 1024; off <<= 1) {
        int v = (tid >= off) ? s_tot[tid - off] : 0;
        __syncthreads();
        s_tot[tid] += v;
        __syncthreads();
    }
    int base = s_tot[tid] - s;
    for (int i = lo; i < hi; i++) {
        starts[i] = base;
        cursor[i] = base;
        base += deg[i];
    }
}

// ---- per-edge: geometry + table-lerp gates + 17-float record ----
// record: [G0, G1*Y1[0..2], G2*Y2[0..4], f1[0..7]]
__global__ __launch_bounds__(256) void edge_kernel(
    const float* __restrict__ pos,
    const int* __restrict__ batch,
    const int* __restrict__ edge_src,
    const int* __restrict__ edge_dst,
    const float* __restrict__ edge_shifts,
    const float* __restrict__ cell,
    const float4* __restrict__ table,
    const float* __restrict__ Ai,
    float* __restrict__ records,
    int* __restrict__ cursor,
    int n_edges)
{
    int e = blockIdx.x * blockDim.x + threadIdx.x;
    if (e >= n_edges) return;

    int src = edge_src[e];
    int dst = edge_dst[e];

    float sh0 = edge_shifts[3 * (size_t)e + 0];
    float sh1 = edge_shifts[3 * (size_t)e + 1];
    float sh2 = edge_shifts[3 * (size_t)e + 2];
    int g = batch[src];
    const float* C = cell + (size_t)g * 9;
    float shx = sh0 * C[0] + sh1 * C[3] + sh2 * C[6];
    float shy = sh0 * C[1] + sh1 * C[4] + sh2 * C[7];
    float shz = sh0 * C[2] + sh1 * C[5] + sh2 * C[8];

    float vx = pos[3 * (size_t)dst + 0] - pos[3 * (size_t)src + 0] + shx;
    float vy = pos[3 * (size_t)dst + 1] - pos[3 * (size_t)src + 1] + shy;
    float vz = pos[3 * (size_t)dst + 2] - pos[3 * (size_t)src + 2] + shz;

    float len = sqrtf(vx * vx + vy * vy + vz * vz);
    float invl = 1.0f / fmaxf(len, 1e-8f);
    float nx = vx * invl, ny = vy * invl, nz = vz * invl;

    // gates via lerp table
    float t = fminf(len * TBL_SCALE, (float)(TBL_N - 1));
    int i0 = (int)t;
    i0 = min(i0, TBL_N - 2);
    float fr = t - (float)i0;
    float4 T0 = table[i0];
    float4 T1 = table[i0 + 1];
    float g0 = fmaf(fr, T1.x - T0.x, T0.x);
    float g1 = fmaf(fr, T1.y - T0.y, T0.y);
    float g2 = fmaf(fr, T1.z - T0.z, T0.z);

    const float s3  = 1.7320508075688772f;
    const float s15 = 3.872983346207417f;
    const float s5  = 2.23606797749979f;
    float Y1_[3] = { s3 * ny, s3 * nz, s3 * nx };
    float Y2_[5] = { s15 * nx * ny, s15 * ny * nz,
                     0.5f * s5 * (3.0f * nz * nz - 1.0f),
                     s15 * nx * nz, 0.5f * s15 * (nx * nx - ny * ny) };

    const float* f1p = Ai + (size_t)src * 8;
    float f1v[8];
    #pragma unroll
    for (int u = 0; u < 8; u++) f1v[u] = f1p[u];

    int slot = atomicAdd(&cursor[dst], 1);
    float* r = records + (size_t)slot * 17;
    r[0] = g0;
    r[1] = g1 * Y1_[0]; r[2] = g1 * Y1_[1]; r[3] = g1 * Y1_[2];
    r[4] = g2 * Y2_[0]; r[5] = g2 * Y2_[1]; r[6] = g2 * Y2_[2];
    r[7] = g2 * Y2_[3]; r[8] = g2 * Y2_[4];
    #pragma unroll
    for (int u = 0; u < 8; u++) r[9 + u] = f1v[u];
}

// ---- one wave per node: streaming M-accumulate, then B/out via LDS ----
__global__ __launch_bounds__(256) void gather_kernel(
    const float* __restrict__ records,
    const int* __restrict__ starts,
    const int* __restrict__ deg,
    const float* __restrict__ Ai,
    const float* __restrict__ tp_w,
    float* __restrict__ out, int n_nodes)
{
    __shared__ float s_tp[3072];     // 3 paths: [pp][u][v][w]
    __shared__ float s_B[4][384];    // per wave: [pp*128 + u*16 + w]
    __shared__ float s_M[4][80];     // per wave: [i'*8 + u], i' in 0..8

    int tid = threadIdx.x;
    for (int t = tid; t < 3072; t += 256) {
        int pp = t >> 10;
        int P = (pp == 0) ? 0 : (pp == 1) ? 3 : 9;
        s_tp[t] = tp_w[P * 1024 + (t & 1023)];
    }
    __syncthreads();

    int wv = tid >> 6;
    int lane = tid & 63;
    int node = blockIdx.x * 4 + wv;
    if (node >= n_nodes) return;

    int start = starts[node];
    int d = deg[node];
    int iq = lane >> 3, u = lane & 7;

    float x2[8];
    #pragma unroll
    for (int v = 0; v < 8; v++) x2[v] = Ai[(size_t)node * 8 + v];

    // phase 1: M accumulation — pure streaming, unroll 4
    float m = 0.0f, m8 = 0.0f;
    const float* recs = records + (size_t)start * 17;
    int j = 0;
    for (; j + 4 <= d; j += 4) {
        const float* r0 = recs + (size_t)(j + 0) * 17;
        const float* r1 = recs + (size_t)(j + 1) * 17;
        const float* r2 = recs + (size_t)(j + 2) * 17;
        const float* r3 = recs + (size_t)(j + 3) * 17;
        float a0 = r0[iq], b0 = r0[8], c0 = r0[9 + u];
        float a1 = r1[iq], b1 = r1[8], c1 = r1[9 + u];
        float a2 = r2[iq], b2 = r2[8], c2 = r2[9 + u];
        float a3 = r3[iq], b3 = r3[8], c3 = r3[9 + u];
        m  = fmaf(a0, c0, m);  m8 = fmaf(b0, c0, m8);
        m  = fmaf(a1, c1, m);  m8 = fmaf(b1, c1, m8);
        m  = fmaf(a2, c2, m);  m8 = fmaf(b2, c2, m8);
        m  = fmaf(a3, c3, m);  m8 = fmaf(b3, c3, m8);
    }
    for (; j < d; j++) {
        const float* r0 = recs + (size_t)j * 17;
        float a0 = r0[iq], b0 = r0[8], c0 = r0[9 + u];
        m  = fmaf(a0, c0, m);
        m8 = fmaf(b0, c0, m8);
    }
    s_M[wv][iq * 8 + u] = m;
    if (lane < 8) s_M[wv][64 + u] = m8;

    // phase 2: B_pp[u][w] = sum_v x2[v] * tp[pp][u][v][w]
    #pragma unroll
    for (int s = 0; s < 6; s++) {
        int t = lane + 64 * s;
        int pp = t >> 7;
        int ub = (t >> 4) & 7;
        int wb = t & 15;
        float acc = 0.0f;
        #pragma unroll
        for (int v = 0; v < 8; v++)
            acc = fmaf(x2[v], s_tp[((pp * 8 + ub) * 8 + v) * 16 + wb], acc);
        s_B[wv][t] = acc;
    }

    // phase 3: 144 contractions of length 8
    float invd = 1.0f / fmaxf((float)d, 1.0f);
    float* row = out + (size_t)node * 144;
    {
        int c = lane;
        int pp, w, ip;
        if (c < 16) { pp = 0; w = c; ip = 0; }
        else { int t = c - 16; pp = 1; w = t / 3; ip = 1 + (t - 3 * (t / 3)); }
        float acc = 0.0f;
        #pragma unroll
        for (int uu = 0; uu < 8; uu++)
            acc = fmaf(s_B[wv][pp * 128 + uu * 16 + w], s_M[wv][ip * 8 + uu], acc);
        row[c] = acc * invd;
    }
    {
        int t = lane;                      // c = 64 + lane
        int w = t / 5; int i = t - 5 * w;
        float acc = 0.0f;
        #pragma unroll
        for (int uu = 0; uu < 8; uu++)
            acc = fmaf(s_B[wv][256 + uu * 16 + w], s_M[wv][(4 + i) * 8 + uu], acc);
        row[64 + lane] = acc * invd;
    }
    if (lane < 16) {
        int t = 64 + lane;                 // c = 128 + lane
        int w = t / 5; int i = t - 5 * w;
        float acc = 0.0f;
        #pragma unroll
        for (int uu = 0; uu < 8; uu++)
            acc = fmaf(s_B[wv][256 + uu * 16 + w], s_M[wv][(4 + i) * 8 + uu], acc);
        row[128 + lane] = acc * invd;
    }
}

extern "C" void kernel_launch(void* const* d_in, const int* in_sizes, int n_in,
                              void* d_out, int out_size, void* d_ws, size_t ws_size,
                              hipStream_t stream)
{
    const float* pos         = (const float*)d_in[0];
    const int*   A           = (const int*)d_in[1];
    const int*   batch       = (const int*)d_in[2];
    const int*   edge_src    = (const int*)d_in[3];
    const int*   edge_dst    = (const int*)d_in[4];
    const float* edge_shifts = (const float*)d_in[5];
    const float* cell        = (const float*)d_in[6];
    const float* emb_table   = (const float*)d_in[7];
    const float* mlp_w1      = (const float*)d_in[8];
    const float* mlp_b1      = (const float*)d_in[9];
    const float* mlp_w2      = (const float*)d_in[10];
    const float* mlp_b2      = (const float*)d_in[11];
    const float* fc_w1       = (const float*)d_in[12];
    const float* fc_b1       = (const float*)d_in[13];
    const float* fc_w2       = (const float*)d_in[14];
    const float* fc_b2       = (const float*)d_in[15];
    const float* fc_w3       = (const float*)d_in[16];
    const float* fc_b3       = (const float*)d_in[17];
    const float* tp_w        = (const float*)d_in[18];

    int n_nodes = in_sizes[1];
    int n_edges = in_sizes[3];
    int n_atom  = in_sizes[7] / 16;

    // ws layout (all float4-aligned where needed)
    float* table   = (float*)d_ws;                        // TBL_N*4 floats
    float* Ai      = table + (size_t)TBL_N * 4;           // n_nodes*8
    int*   deg     = (int*)(Ai + (size_t)n_nodes * 8);    // n_nodes
    int*   starts  = deg + n_nodes;                       // n_nodes
    int*   cursor  = starts + n_nodes;                    // n_nodes
    float* records = (float*)(cursor + n_nodes);          // n_edges*17

    hipMemsetAsync(deg, 0, (size_t)n_nodes * sizeof(int), stream);

    ai_kernel<<<(n_nodes + 255) / 256, 256, 0, stream>>>(
        A, emb_table, mlp_w1, mlp_b1, mlp_w2, mlp_b2, Ai, n_nodes, n_atom);

    table_kernel<<<TBL_N / 256, 256, 0, stream>>>(
        fc_w1, fc_b1, fc_w2, fc_b2, fc_w3, fc_b3, (float4*)table);

    deg_kernel<<<(n_edges + 255) / 256, 256, 0, stream>>>(edge_dst, deg, n_edges);

    scan_kernel<<<1, 1024, 0, stream>>>(deg, starts, cursor, n_nodes);

    edge_kernel<<<(n_edges + 255) / 256, 256, 0, stream>>>(
        pos, batch, edge_src, edge_dst, edge_shifts, cell,
        (const float4*)table, Ai, records, cursor, n_edges);

    gather_kernel<<<(n_nodes + 3) / 4, 256, 0, stream>>>(
        records, starts, deg, Ai, tp_w, (float*)d_out, n_nodes);
}

// Round 5
// 177.695 us; speedup vs baseline: 21.1443x; 1.4628x over previous
//
#include <hip/hip_runtime.h>
#include <cstddef>

// ICTDIrrepsE3Conv — round 5.
//  - gates = f(edge_length) only -> 8192-entry lerp table
//  - Ai has only MAX_ATOM=10 distinct rows -> per-block LDS compute + copy
//  - edge record carries f1 = Ai[src] (17 floats) -> streaming gather
//  - NEW: multi-block CSR scan (partial-sum + scan-write), replaces the
//    92 us single-block scan that dominated round 4.

#define TBL_N 8192
#define TBL_SCALE 1024.0f   // TBL_N / 8.0 range

__device__ __forceinline__ float silu(float x) {
    return x / (1.0f + __expf(-x));
}

// ---- gates lookup table build ----
__global__ __launch_bounds__(256) void table_kernel(
    const float* __restrict__ fc_w1, const float* __restrict__ fc_b1,
    const float* __restrict__ fc_w2, const float* __restrict__ fc_b2,
    const float* __restrict__ fc_w3, const float* __restrict__ fc_b3,
    float4* __restrict__ table)
{
    int i = blockIdx.x * blockDim.x + threadIdx.x;
    if (i >= TBL_N) return;
    float len = (float)i * (1.0f / TBL_SCALE);

    float emb[16];
    const float inv_step = 17.0f / 5.0f;
    #pragma unroll
    for (int b = 0; b < 16; b++) {
        float d = len * inv_step - (float)(b + 1);
        emb[b] = __expf(-d * d) * 3.5714285714285716f; // 4/1.12
    }
    float h1[64];
    #pragma unroll
    for (int k = 0; k < 64; k++) {
        float acc = fc_b1[k];
        #pragma unroll
        for (int b = 0; b < 16; b++) acc = fmaf(emb[b], fc_w1[b * 64 + k], acc);
        h1[k] = silu(acc);
    }
    float g0 = fc_b3[0], g3 = fc_b3[3], g9 = fc_b3[9];
    for (int k = 0; k < 64; k++) {
        float acc = fc_b2[k];
        #pragma unroll
        for (int j = 0; j < 64; j++) acc = fmaf(h1[j], fc_w2[j * 64 + k], acc);
        float h2 = silu(acc);
        g0 = fmaf(h2, fc_w3[k * 15 + 0], g0);
        g3 = fmaf(h2, fc_w3[k * 15 + 3], g3);
        g9 = fmaf(h2, fc_w3[k * 15 + 9], g9);
    }
    table[i] = make_float4(g0 * 0.125f, g3 * 0.125f, g9 * 0.125f, 0.0f);
}

// ---- Ai: n_atom distinct rows computed redundantly per block, then copy ----
__global__ __launch_bounds__(256) void ai_kernel(
    const int* __restrict__ A, const float* __restrict__ emb_table,
    const float* __restrict__ w1, const float* __restrict__ b1,
    const float* __restrict__ w2, const float* __restrict__ b2,
    float* __restrict__ Ai, int n_nodes, int n_atom)
{
    __shared__ float s_rows[16 * 8];
    int tid = threadIdx.x;
    if (tid < n_atom * 8) {
        int a = tid >> 3, j = tid & 7;
        float e[16];
        #pragma unroll
        for (int i = 0; i < 16; i++) e[i] = emb_table[a * 16 + i];
        float acc_j = b2[j];
        for (int k = 0; k < 64; k++) {
            float acc = b1[k];
            #pragma unroll
            for (int i = 0; i < 16; i++) acc = fmaf(e[i], w1[i * 64 + k], acc);
            acc_j = fmaf(silu(acc), w2[k * 8 + j], acc_j);
        }
        s_rows[tid] = acc_j;
    }
    __syncthreads();
    int n = blockIdx.x * blockDim.x + tid;
    if (n >= n_nodes) return;
    int a = A[n];
    #pragma unroll
    for (int j = 0; j < 8; j++) Ai[(size_t)n * 8 + j] = s_rows[a * 8 + j];
}

__global__ __launch_bounds__(256) void deg_kernel(
    const int* __restrict__ edge_dst, int* __restrict__ deg, int n_edges)
{
    int e = blockIdx.x * blockDim.x + threadIdx.x;
    if (e >= n_edges) return;
    atomicAdd(&deg[edge_dst[e]], 1);
}

// ---- multi-block scan, stage 1: per-block sums ----
__global__ __launch_bounds__(1024) void partial_kernel(
    const int* __restrict__ deg, int* __restrict__ bsum, int n)
{
    __shared__ int red[1024];
    int tid = threadIdx.x;
    int i = blockIdx.x * 1024 + tid;
    red[tid] = (i < n) ? deg[i] : 0;
    __syncthreads();
    #pragma unroll
    for (int off = 512; off > 0; off >>= 1) {
        if (tid < off) red[tid] += red[tid + off];
        __syncthreads();
    }
    if (tid == 0) bsum[blockIdx.x] = red[0];
}

// ---- stage 2: per-block scan + base from scanned bsum (replicated) ----
__global__ __launch_bounds__(1024) void scan_write_kernel(
    const int* __restrict__ deg, const int* __restrict__ bsum,
    int* __restrict__ starts, int* __restrict__ cursor, int n, int nb)
{
    __shared__ int s[1024];
    __shared__ int sb[1024];
    int tid = threadIdx.x;

    sb[tid] = (tid < nb) ? bsum[tid] : 0;
    int i = blockIdx.x * 1024 + tid;
    int v = (i < n) ? deg[i] : 0;
    s[tid] = v;
    __syncthreads();
    #pragma unroll
    for (int off = 1; off < 1024; off <<= 1) {
        int t1 = (tid >= off) ? s[tid - off] : 0;
        int t2 = (tid >= off) ? sb[tid - off] : 0;
        __syncthreads();
        s[tid] += t1;
        sb[tid] += t2;
        __syncthreads();
    }
    int base = (blockIdx.x == 0) ? 0 : sb[blockIdx.x - 1];
    if (i < n) {
        int excl = base + s[tid] - v;
        starts[i] = excl;
        cursor[i] = excl;
    }
}

// ---- per-edge: geometry + table-lerp gates + 17-float record ----
// record: [G0, G1*Y1[0..2], G2*Y2[0..4], f1[0..7]]
__global__ __launch_bounds__(256) void edge_kernel(
    const float* __restrict__ pos,
    const int* __restrict__ batch,
    const int* __restrict__ edge_src,
    const int* __restrict__ edge_dst,
    const float* __restrict__ edge_shifts,
    const float* __restrict__ cell,
    const float4* __restrict__ table,
    const float* __restrict__ Ai,
    float* __restrict__ records,
    int* __restrict__ cursor,
    int n_edges)
{
    int e = blockIdx.x * blockDim.x + threadIdx.x;
    if (e >= n_edges) return;

    int src = edge_src[e];
    int dst = edge_dst[e];

    float sh0 = edge_shifts[3 * (size_t)e + 0];
    float sh1 = edge_shifts[3 * (size_t)e + 1];
    float sh2 = edge_shifts[3 * (size_t)e + 2];
    int g = batch[src];
    const float* C = cell + (size_t)g * 9;
    float shx = sh0 * C[0] + sh1 * C[3] + sh2 * C[6];
    float shy = sh0 * C[1] + sh1 * C[4] + sh2 * C[7];
    float shz = sh0 * C[2] + sh1 * C[5] + sh2 * C[8];

    float vx = pos[3 * (size_t)dst + 0] - pos[3 * (size_t)src + 0] + shx;
    float vy = pos[3 * (size_t)dst + 1] - pos[3 * (size_t)src + 1] + shy;
    float vz = pos[3 * (size_t)dst + 2] - pos[3 * (size_t)src + 2] + shz;

    float len = sqrtf(vx * vx + vy * vy + vz * vz);
    float invl = 1.0f / fmaxf(len, 1e-8f);
    float nx = vx * invl, ny = vy * invl, nz = vz * invl;

    float t = fminf(len * TBL_SCALE, (float)(TBL_N - 1));
    int i0 = (int)t;
    i0 = min(i0, TBL_N - 2);
    float fr = t - (float)i0;
    float4 T0 = table[i0];
    float4 T1 = table[i0 + 1];
    float g0 = fmaf(fr, T1.x - T0.x, T0.x);
    float g1 = fmaf(fr, T1.y - T0.y, T0.y);
    float g2 = fmaf(fr, T1.z - T0.z, T0.z);

    const float s3  = 1.7320508075688772f;
    const float s15 = 3.872983346207417f;
    const float s5  = 2.23606797749979f;
    float Y1_[3] = { s3 * ny, s3 * nz, s3 * nx };
    float Y2_[5] = { s15 * nx * ny, s15 * ny * nz,
                     0.5f * s5 * (3.0f * nz * nz - 1.0f),
                     s15 * nx * nz, 0.5f * s15 * (nx * nx - ny * ny) };

    const float* f1p = Ai + (size_t)src * 8;
    float f1v[8];
    #pragma unroll
    for (int u = 0; u < 8; u++) f1v[u] = f1p[u];

    int slot = atomicAdd(&cursor[dst], 1);
    float* r = records + (size_t)slot * 17;
    r[0] = g0;
    r[1] = g1 * Y1_[0]; r[2] = g1 * Y1_[1]; r[3] = g1 * Y1_[2];
    r[4] = g2 * Y2_[0]; r[5] = g2 * Y2_[1]; r[6] = g2 * Y2_[2];
    r[7] = g2 * Y2_[3]; r[8] = g2 * Y2_[4];
    #pragma unroll
    for (int u = 0; u < 8; u++) r[9 + u] = f1v[u];
}

// ---- one wave per node: streaming M-accumulate, then B/out via LDS ----
__global__ __launch_bounds__(256) void gather_kernel(
    const float* __restrict__ records,
    const int* __restrict__ starts,
    const int* __restrict__ deg,
    const float* __restrict__ Ai,
    const float* __restrict__ tp_w,
    float* __restrict__ out, int n_nodes)
{
    __shared__ float s_tp[3072];     // 3 paths: [pp][u][v][w]
    __shared__ float s_B[4][384];    // per wave: [pp*128 + u*16 + w]
    __shared__ float s_M[4][80];     // per wave: [i'*8 + u], i' in 0..8

    int tid = threadIdx.x;
    for (int t = tid; t < 3072; t += 256) {
        int pp = t >> 10;
        int P = (pp == 0) ? 0 : (pp == 1) ? 3 : 9;
        s_tp[t] = tp_w[P * 1024 + (t & 1023)];
    }
    __syncthreads();

    int wv = tid >> 6;
    int lane = tid & 63;
    int node = blockIdx.x * 4 + wv;
    if (node >= n_nodes) return;

    int start = starts[node];
    int d = deg[node];
    int iq = lane >> 3, u = lane & 7;

    float x2[8];
    #pragma unroll
    for (int v = 0; v < 8; v++) x2[v] = Ai[(size_t)node * 8 + v];

    // phase 1: streaming M accumulation, unroll 4
    float m = 0.0f, m8 = 0.0f;
    const float* recs = records + (size_t)start * 17;
    int j = 0;
    for (; j + 4 <= d; j += 4) {
        const float* r0 = recs + (size_t)(j + 0) * 17;
        const float* r1 = recs + (size_t)(j + 1) * 17;
        const float* r2 = recs + (size_t)(j + 2) * 17;
        const float* r3 = recs + (size_t)(j + 3) * 17;
        float a0 = r0[iq], b0 = r0[8], c0 = r0[9 + u];
        float a1 = r1[iq], b1 = r1[8], c1 = r1[9 + u];
        float a2 = r2[iq], b2 = r2[8], c2 = r2[9 + u];
        float a3 = r3[iq], b3 = r3[8], c3 = r3[9 + u];
        m  = fmaf(a0, c0, m);  m8 = fmaf(b0, c0, m8);
        m  = fmaf(a1, c1, m);  m8 = fmaf(b1, c1, m8);
        m  = fmaf(a2, c2, m);  m8 = fmaf(b2, c2, m8);
        m  = fmaf(a3, c3, m);  m8 = fmaf(b3, c3, m8);
    }
    for (; j < d; j++) {
        const float* r0 = recs + (size_t)j * 17;
        float a0 = r0[iq], b0 = r0[8], c0 = r0[9 + u];
        m  = fmaf(a0, c0, m);
        m8 = fmaf(b0, c0, m8);
    }
    s_M[wv][iq * 8 + u] = m;
    if (lane < 8) s_M[wv][64 + u] = m8;

    // phase 2: B_pp[u][w] = sum_v x2[v] * tp[pp][u][v][w]
    #pragma unroll
    for (int s = 0; s < 6; s++) {
        int t = lane + 64 * s;
        int pp = t >> 7;
        int ub = (t >> 4) & 7;
        int wb = t & 15;
        float acc = 0.0f;
        #pragma unroll
        for (int v = 0; v < 8; v++)
            acc = fmaf(x2[v], s_tp[((pp * 8 + ub) * 8 + v) * 16 + wb], acc);
        s_B[wv][t] = acc;
    }

    // phase 3: 144 contractions of length 8
    float invd = 1.0f / fmaxf((float)d, 1.0f);
    float* row = out + (size_t)node * 144;
    {
        int c = lane;
        int pp, w, ip;
        if (c < 16) { pp = 0; w = c; ip = 0; }
        else { int t = c - 16; pp = 1; w = t / 3; ip = 1 + (t - 3 * (t / 3)); }
        float acc = 0.0f;
        #pragma unroll
        for (int uu = 0; uu < 8; uu++)
            acc = fmaf(s_B[wv][pp * 128 + uu * 16 + w], s_M[wv][ip * 8 + uu], acc);
        row[c] = acc * invd;
    }
    {
        int t = lane;                      // c = 64 + lane
        int w = t / 5; int i = t - 5 * w;
        float acc = 0.0f;
        #pragma unroll
        for (int uu = 0; uu < 8; uu++)
            acc = fmaf(s_B[wv][256 + uu * 16 + w], s_M[wv][(4 + i) * 8 + uu], acc);
        row[64 + lane] = acc * invd;
    }
    if (lane < 16) {
        int t = 64 + lane;                 // c = 128 + lane
        int w = t / 5; int i = t - 5 * w;
        float acc = 0.0f;
        #pragma unroll
        for (int uu = 0; uu < 8; uu++)
            acc = fmaf(s_B[wv][256 + uu * 16 + w], s_M[wv][(4 + i) * 8 + uu], acc);
        row[128 + lane] = acc * invd;
    }
}

extern "C" void kernel_launch(void* const* d_in, const int* in_sizes, int n_in,
                              void* d_out, int out_size, void* d_ws, size_t ws_size,
                              hipStream_t stream)
{
    const float* pos         = (const float*)d_in[0];
    const int*   A           = (const int*)d_in[1];
    const int*   batch       = (const int*)d_in[2];
    const int*   edge_src    = (const int*)d_in[3];
    const int*   edge_dst    = (const int*)d_in[4];
    const float* edge_shifts = (const float*)d_in[5];
    const float* cell        = (const float*)d_in[6];
    const float* emb_table   = (const float*)d_in[7];
    const float* mlp_w1      = (const float*)d_in[8];
    const float* mlp_b1      = (const float*)d_in[9];
    const float* mlp_w2      = (const float*)d_in[10];
    const float* mlp_b2      = (const float*)d_in[11];
    const float* fc_w1       = (const float*)d_in[12];
    const float* fc_b1       = (const float*)d_in[13];
    const float* fc_w2       = (const float*)d_in[14];
    const float* fc_b2       = (const float*)d_in[15];
    const float* fc_w3       = (const float*)d_in[16];
    const float* fc_b3       = (const float*)d_in[17];
    const float* tp_w        = (const float*)d_in[18];

    int n_nodes = in_sizes[1];
    int n_edges = in_sizes[3];
    int n_atom  = in_sizes[7] / 16;
    int nb      = (n_nodes + 1023) / 1024;

    // ws layout
    float* table   = (float*)d_ws;                        // TBL_N*4 floats
    float* Ai      = table + (size_t)TBL_N * 4;           // n_nodes*8
    int*   deg     = (int*)(Ai + (size_t)n_nodes * 8);    // n_nodes
    int*   starts  = deg + n_nodes;                       // n_nodes
    int*   cursor  = starts + n_nodes;                    // n_nodes
    int*   bsum    = cursor + n_nodes;                    // nb (<=1024)
    float* records = (float*)(bsum + 1024);               // n_edges*17

    hipMemsetAsync(deg, 0, (size_t)n_nodes * sizeof(int), stream);

    ai_kernel<<<(n_nodes + 255) / 256, 256, 0, stream>>>(
        A, emb_table, mlp_w1, mlp_b1, mlp_w2, mlp_b2, Ai, n_nodes, n_atom);

    table_kernel<<<TBL_N / 256, 256, 0, stream>>>(
        fc_w1, fc_b1, fc_w2, fc_b2, fc_w3, fc_b3, (float4*)table);

    deg_kernel<<<(n_edges + 255) / 256, 256, 0, stream>>>(edge_dst, deg, n_edges);

    partial_kernel<<<nb, 1024, 0, stream>>>(deg, bsum, n_nodes);

    scan_write_kernel<<<nb, 1024, 0, stream>>>(deg, bsum, starts, cursor,
                                               n_nodes, nb);

    edge_kernel<<<(n_edges + 255) / 256, 256, 0, stream>>>(
        pos, batch, edge_src, edge_dst, edge_shifts, cell,
        (const float4*)table, Ai, records, cursor, n_edges);

    gather_kernel<<<(n_nodes + 3) / 4, 256, 0, stream>>>(
        records, starts, deg, Ai, tp_w, (float*)d_out, n_nodes);
}

// Round 6
// 134.175 us; speedup vs baseline: 28.0025x; 1.3244x over previous
//
#include <hip/hip_runtime.h>
#include <cstddef>

// ICTDIrrepsE3Conv — round 6.
//  - gates = f(edge_length) only -> 8192-entry lerp table
//  - NEW: table built wave-parallel (1 wave/sample, lanes=neurons) — replaces
//    the 53 us 32-block latency-bound builder that topped round 5.
//  - Ai has only MAX_ATOM=10 distinct rows -> per-block LDS compute + copy
//  - edge record carries f1 = Ai[src] (17 floats) -> streaming gather
//  - multi-block CSR scan (partial-sum + scan-write)

#define TBL_N 8192
#define TBL_SCALE 1024.0f   // TBL_N / 8.0 range

__device__ __forceinline__ float silu(float x) {
    return x / (1.0f + __expf(-x));
}

// ---- gates lookup table: 1 wave per sample, lanes = neuron k ----
__global__ __launch_bounds__(256) void table_kernel(
    const float* __restrict__ fc_w1, const float* __restrict__ fc_b1,
    const float* __restrict__ fc_w2, const float* __restrict__ fc_b2,
    const float* __restrict__ fc_w3, const float* __restrict__ fc_b3,
    float4* __restrict__ table)
{
    __shared__ float s_h1[4][64];
    int tid = threadIdx.x;
    int s = tid >> 6;       // sample slot in block (= wave id)
    int k = tid & 63;       // neuron index
    int samp = blockIdx.x * 4 + s;
    float len = (float)samp * (1.0f / TBL_SCALE);

    // radial basis (redundant per lane, cheap)
    float emb[16];
    const float inv_step = 17.0f / 5.0f;
    #pragma unroll
    for (int b = 0; b < 16; b++) {
        float d = len * inv_step - (float)(b + 1);
        emb[b] = __expf(-d * d) * 3.5714285714285716f; // 4/1.12
    }

    // layer 1: lane k owns h1[k]
    float acc = fc_b1[k];
    #pragma unroll
    for (int b = 0; b < 16; b++) acc = fmaf(emb[b], fc_w1[b * 64 + k], acc);
    s_h1[s][k] = silu(acc);
    __syncthreads();

    // layer 2: lane k owns h2[k]; h1[j] via uniform LDS broadcast
    float acc2 = fc_b2[k];
    #pragma unroll
    for (int j = 0; j < 64; j++)
        acc2 = fmaf(s_h1[s][j], fc_w2[j * 64 + k], acc2);
    float h2 = silu(acc2);

    // gates: per-lane partials, wave reduce
    float p0 = h2 * fc_w3[k * 15 + 0];
    float p3 = h2 * fc_w3[k * 15 + 3];
    float p9 = h2 * fc_w3[k * 15 + 9];
    #pragma unroll
    for (int off = 32; off > 0; off >>= 1) {
        p0 += __shfl_down(p0, off, 64);
        p3 += __shfl_down(p3, off, 64);
        p9 += __shfl_down(p9, off, 64);
    }
    if (k == 0) {
        table[samp] = make_float4((fc_b3[0] + p0) * 0.125f,
                                  (fc_b3[3] + p3) * 0.125f,
                                  (fc_b3[9] + p9) * 0.125f, 0.0f);
    }
}

// ---- Ai: n_atom distinct rows computed redundantly per block, then copy ----
__global__ __launch_bounds__(256) void ai_kernel(
    const int* __restrict__ A, const float* __restrict__ emb_table,
    const float* __restrict__ w1, const float* __restrict__ b1,
    const float* __restrict__ w2, const float* __restrict__ b2,
    float* __restrict__ Ai, int n_nodes, int n_atom)
{
    __shared__ float s_rows[16 * 8];
    int tid = threadIdx.x;
    if (tid < n_atom * 8) {
        int a = tid >> 3, j = tid & 7;
        float e[16];
        #pragma unroll
        for (int i = 0; i < 16; i++) e[i] = emb_table[a * 16 + i];
        float acc_j = b2[j];
        for (int k = 0; k < 64; k++) {
            float acc = b1[k];
            #pragma unroll
            for (int i = 0; i < 16; i++) acc = fmaf(e[i], w1[i * 64 + k], acc);
            acc_j = fmaf(silu(acc), w2[k * 8 + j], acc_j);
        }
        s_rows[tid] = acc_j;
    }
    __syncthreads();
    int n = blockIdx.x * blockDim.x + tid;
    if (n >= n_nodes) return;
    int a = A[n];
    #pragma unroll
    for (int j = 0; j < 8; j++) Ai[(size_t)n * 8 + j] = s_rows[a * 8 + j];
}

__global__ __launch_bounds__(256) void deg_kernel(
    const int* __restrict__ edge_dst, int* __restrict__ deg, int n_edges)
{
    int e = blockIdx.x * blockDim.x + threadIdx.x;
    if (e >= n_edges) return;
    atomicAdd(&deg[edge_dst[e]], 1);
}

// ---- multi-block scan, stage 1: per-block sums ----
__global__ __launch_bounds__(1024) void partial_kernel(
    const int* __restrict__ deg, int* __restrict__ bsum, int n)
{
    __shared__ int red[1024];
    int tid = threadIdx.x;
    int i = blockIdx.x * 1024 + tid;
    red[tid] = (i < n) ? deg[i] : 0;
    __syncthreads();
    #pragma unroll
    for (int off = 512; off > 0; off >>= 1) {
        if (tid < off) red[tid] += red[tid + off];
        __syncthreads();
    }
    if (tid == 0) bsum[blockIdx.x] = red[0];
}

// ---- stage 2: per-block scan + base from scanned bsum (replicated) ----
__global__ __launch_bounds__(1024) void scan_write_kernel(
    const int* __restrict__ deg, const int* __restrict__ bsum,
    int* __restrict__ starts, int* __restrict__ cursor, int n, int nb)
{
    __shared__ int s[1024];
    __shared__ int sb[1024];
    int tid = threadIdx.x;

    sb[tid] = (tid < nb) ? bsum[tid] : 0;
    int i = blockIdx.x * 1024 + tid;
    int v = (i < n) ? deg[i] : 0;
    s[tid] = v;
    __syncthreads();
    #pragma unroll
    for (int off = 1; off < 1024; off <<= 1) {
        int t1 = (tid >= off) ? s[tid - off] : 0;
        int t2 = (tid >= off) ? sb[tid - off] : 0;
        __syncthreads();
        s[tid] += t1;
        sb[tid] += t2;
        __syncthreads();
    }
    int base = (blockIdx.x == 0) ? 0 : sb[blockIdx.x - 1];
    if (i < n) {
        int excl = base + s[tid] - v;
        starts[i] = excl;
        cursor[i] = excl;
    }
}

// ---- per-edge: geometry + table-lerp gates + 17-float record ----
// record: [G0, G1*Y1[0..2], G2*Y2[0..4], f1[0..7]]
__global__ __launch_bounds__(256) void edge_kernel(
    const float* __restrict__ pos,
    const int* __restrict__ batch,
    const int* __restrict__ edge_src,
    const int* __restrict__ edge_dst,
    const float* __restrict__ edge_shifts,
    const float* __restrict__ cell,
    const float4* __restrict__ table,
    const float* __restrict__ Ai,
    float* __restrict__ records,
    int* __restrict__ cursor,
    int n_edges)
{
    int e = blockIdx.x * blockDim.x + threadIdx.x;
    if (e >= n_edges) return;

    int src = edge_src[e];
    int dst = edge_dst[e];

    float sh0 = edge_shifts[3 * (size_t)e + 0];
    float sh1 = edge_shifts[3 * (size_t)e + 1];
    float sh2 = edge_shifts[3 * (size_t)e + 2];
    int g = batch[src];
    const float* C = cell + (size_t)g * 9;
    float shx = sh0 * C[0] + sh1 * C[3] + sh2 * C[6];
    float shy = sh0 * C[1] + sh1 * C[4] + sh2 * C[7];
    float shz = sh0 * C[2] + sh1 * C[5] + sh2 * C[8];

    float vx = pos[3 * (size_t)dst + 0] - pos[3 * (size_t)src + 0] + shx;
    float vy = pos[3 * (size_t)dst + 1] - pos[3 * (size_t)src + 1] + shy;
    float vz = pos[3 * (size_t)dst + 2] - pos[3 * (size_t)src + 2] + shz;

    float len = sqrtf(vx * vx + vy * vy + vz * vz);
    float invl = 1.0f / fmaxf(len, 1e-8f);
    float nx = vx * invl, ny = vy * invl, nz = vz * invl;

    float t = fminf(len * TBL_SCALE, (float)(TBL_N - 1));
    int i0 = (int)t;
    i0 = min(i0, TBL_N - 2);
    float fr = t - (float)i0;
    float4 T0 = table[i0];
    float4 T1 = table[i0 + 1];
    float g0 = fmaf(fr, T1.x - T0.x, T0.x);
    float g1 = fmaf(fr, T1.y - T0.y, T0.y);
    float g2 = fmaf(fr, T1.z - T0.z, T0.z);

    const float s3  = 1.7320508075688772f;
    const float s15 = 3.872983346207417f;
    const float s5  = 2.23606797749979f;
    float Y1_[3] = { s3 * ny, s3 * nz, s3 * nx };
    float Y2_[5] = { s15 * nx * ny, s15 * ny * nz,
                     0.5f * s5 * (3.0f * nz * nz - 1.0f),
                     s15 * nx * nz, 0.5f * s15 * (nx * nx - ny * ny) };

    const float* f1p = Ai + (size_t)src * 8;
    float f1v[8];
    #pragma unroll
    for (int u = 0; u < 8; u++) f1v[u] = f1p[u];

    int slot = atomicAdd(&cursor[dst], 1);
    float* r = records + (size_t)slot * 17;
    r[0] = g0;
    r[1] = g1 * Y1_[0]; r[2] = g1 * Y1_[1]; r[3] = g1 * Y1_[2];
    r[4] = g2 * Y2_[0]; r[5] = g2 * Y2_[1]; r[6] = g2 * Y2_[2];
    r[7] = g2 * Y2_[3]; r[8] = g2 * Y2_[4];
    #pragma unroll
    for (int u = 0; u < 8; u++) r[9 + u] = f1v[u];
}

// ---- one wave per node: streaming M-accumulate, then B/out via LDS ----
__global__ __launch_bounds__(256) void gather_kernel(
    const float* __restrict__ records,
    const int* __restrict__ starts,
    const int* __restrict__ deg,
    const float* __restrict__ Ai,
    const float* __restrict__ tp_w,
    float* __restrict__ out, int n_nodes)
{
    __shared__ float s_tp[3072];     // 3 paths: [pp][u][v][w]
    __shared__ float s_B[4][384];    // per wave: [pp*128 + u*16 + w]
    __shared__ float s_M[4][80];     // per wave: [i'*8 + u], i' in 0..8

    int tid = threadIdx.x;
    for (int t = tid; t < 3072; t += 256) {
        int pp = t >> 10;
        int P = (pp == 0) ? 0 : (pp == 1) ? 3 : 9;
        s_tp[t] = tp_w[P * 1024 + (t & 1023)];
    }
    __syncthreads();

    int wv = tid >> 6;
    int lane = tid & 63;
    int node = blockIdx.x * 4 + wv;
    if (node >= n_nodes) return;

    int start = starts[node];
    int d = deg[node];
    int iq = lane >> 3, u = lane & 7;

    float x2[8];
    #pragma unroll
    for (int v = 0; v < 8; v++) x2[v] = Ai[(size_t)node * 8 + v];

    // phase 1: streaming M accumulation, unroll 4
    float m = 0.0f, m8 = 0.0f;
    const float* recs = records + (size_t)start * 17;
    int j = 0;
    for (; j + 4 <= d; j += 4) {
        const float* r0 = recs + (size_t)(j + 0) * 17;
        const float* r1 = recs + (size_t)(j + 1) * 17;
        const float* r2 = recs + (size_t)(j + 2) * 17;
        const float* r3 = recs + (size_t)(j + 3) * 17;
        float a0 = r0[iq], b0 = r0[8], c0 = r0[9 + u];
        float a1 = r1[iq], b1 = r1[8], c1 = r1[9 + u];
        float a2 = r2[iq], b2 = r2[8], c2 = r2[9 + u];
        float a3 = r3[iq], b3 = r3[8], c3 = r3[9 + u];
        m  = fmaf(a0, c0, m);  m8 = fmaf(b0, c0, m8);
        m  = fmaf(a1, c1, m);  m8 = fmaf(b1, c1, m8);
        m  = fmaf(a2, c2, m);  m8 = fmaf(b2, c2, m8);
        m  = fmaf(a3, c3, m);  m8 = fmaf(b3, c3, m8);
    }
    for (; j < d; j++) {
        const float* r0 = recs + (size_t)j * 17;
        float a0 = r0[iq], b0 = r0[8], c0 = r0[9 + u];
        m  = fmaf(a0, c0, m);
        m8 = fmaf(b0, c0, m8);
    }
    s_M[wv][iq * 8 + u] = m;
    if (lane < 8) s_M[wv][64 + u] = m8;

    // phase 2: B_pp[u][w] = sum_v x2[v] * tp[pp][u][v][w]
    #pragma unroll
    for (int s = 0; s < 6; s++) {
        int t = lane + 64 * s;
        int pp = t >> 7;
        int ub = (t >> 4) & 7;
        int wb = t & 15;
        float acc = 0.0f;
        #pragma unroll
        for (int v = 0; v < 8; v++)
            acc = fmaf(x2[v], s_tp[((pp * 8 + ub) * 8 + v) * 16 + wb], acc);
        s_B[wv][t] = acc;
    }

    // phase 3: 144 contractions of length 8
    float invd = 1.0f / fmaxf((float)d, 1.0f);
    float* row = out + (size_t)node * 144;
    {
        int c = lane;
        int pp, w, ip;
        if (c < 16) { pp = 0; w = c; ip = 0; }
        else { int t = c - 16; pp = 1; w = t / 3; ip = 1 + (t - 3 * (t / 3)); }
        float acc = 0.0f;
        #pragma unroll
        for (int uu = 0; uu < 8; uu++)
            acc = fmaf(s_B[wv][pp * 128 + uu * 16 + w], s_M[wv][ip * 8 + uu], acc);
        row[c] = acc * invd;
    }
    {
        int t = lane;                      // c = 64 + lane
        int w = t / 5; int i = t - 5 * w;
        float acc = 0.0f;
        #pragma unroll
        for (int uu = 0; uu < 8; uu++)
            acc = fmaf(s_B[wv][256 + uu * 16 + w], s_M[wv][(4 + i) * 8 + uu], acc);
        row[64 + lane] = acc * invd;
    }
    if (lane < 16) {
        int t = 64 + lane;                 // c = 128 + lane
        int w = t / 5; int i = t - 5 * w;
        float acc = 0.0f;
        #pragma unroll
        for (int uu = 0; uu < 8; uu++)
            acc = fmaf(s_B[wv][256 + uu * 16 + w], s_M[wv][(4 + i) * 8 + uu], acc);
        row[128 + lane] = acc * invd;
    }
}

extern "C" void kernel_launch(void* const* d_in, const int* in_sizes, int n_in,
                              void* d_out, int out_size, void* d_ws, size_t ws_size,
                              hipStream_t stream)
{
    const float* pos         = (const float*)d_in[0];
    const int*   A           = (const int*)d_in[1];
    const int*   batch       = (const int*)d_in[2];
    const int*   edge_src    = (const int*)d_in[3];
    const int*   edge_dst    = (const int*)d_in[4];
    const float* edge_shifts = (const float*)d_in[5];
    const float* cell        = (const float*)d_in[6];
    const float* emb_table   = (const float*)d_in[7];
    const float* mlp_w1      = (const float*)d_in[8];
    const float* mlp_b1      = (const float*)d_in[9];
    const float* mlp_w2      = (const float*)d_in[10];
    const float* mlp_b2      = (const float*)d_in[11];
    const float* fc_w1       = (const float*)d_in[12];
    const float* fc_b1       = (const float*)d_in[13];
    const float* fc_w2       = (const float*)d_in[14];
    const float* fc_b2       = (const float*)d_in[15];
    const float* fc_w3       = (const float*)d_in[16];
    const float* fc_b3       = (const float*)d_in[17];
    const float* tp_w        = (const float*)d_in[18];

    int n_nodes = in_sizes[1];
    int n_edges = in_sizes[3];
    int n_atom  = in_sizes[7] / 16;
    int nb      = (n_nodes + 1023) / 1024;

    // ws layout
    float* table   = (float*)d_ws;                        // TBL_N*4 floats
    float* Ai      = table + (size_t)TBL_N * 4;           // n_nodes*8
    int*   deg     = (int*)(Ai + (size_t)n_nodes * 8);    // n_nodes
    int*   starts  = deg + n_nodes;                       // n_nodes
    int*   cursor  = starts + n_nodes;                    // n_nodes
    int*   bsum    = cursor + n_nodes;                    // nb (<=1024)
    float* records = (float*)(bsum + 1024);               // n_edges*17

    hipMemsetAsync(deg, 0, (size_t)n_nodes * sizeof(int), stream);

    ai_kernel<<<(n_nodes + 255) / 256, 256, 0, stream>>>(
        A, emb_table, mlp_w1, mlp_b1, mlp_w2, mlp_b2, Ai, n_nodes, n_atom);

    table_kernel<<<TBL_N / 4, 256, 0, stream>>>(
        fc_w1, fc_b1, fc_w2, fc_b2, fc_w3, fc_b3, (float4*)table);

    deg_kernel<<<(n_edges + 255) / 256, 256, 0, stream>>>(edge_dst, deg, n_edges);

    partial_kernel<<<nb, 1024, 0, stream>>>(deg, bsum, n_nodes);

    scan_write_kernel<<<nb, 1024, 0, stream>>>(deg, bsum, starts, cursor,
                                               n_nodes, nb);

    edge_kernel<<<(n_edges + 255) / 256, 256, 0, stream>>>(
        pos, batch, edge_src, edge_dst, edge_shifts, cell,
        (const float4*)table, Ai, records, cursor, n_edges);

    gather_kernel<<<(n_nodes + 3) / 4, 256, 0, stream>>>(
        records, starts, deg, Ai, tp_w, (float*)d_out, n_nodes);
}

// Round 7
// 130.840 us; speedup vs baseline: 28.7162x; 1.0255x over previous
//
#include <hip/hip_runtime.h>
#include <cstddef>

// ICTDIrrepsE3Conv — round 7.
//  - gates = f(edge_length) only -> 8192-entry lerp table (wave-parallel build)
//  - atom-type factorization: rows[10][8] and B[10][3][8][16] precomputed
//    (x2 and f1 depend only on A[n], MAX_ATOM=10) -> gather phase 2 deleted,
//    edge records carry a_src instead of f1 (17 -> 12 floats)
//  - CSR gather: streaming M accumulation + per-atom B finish, no atomics on out
//  - multi-block CSR scan

#define TBL_N 8192
#define TBL_SCALE 1024.0f   // TBL_N / 8.0 range

__device__ __forceinline__ float silu(float x) {
    return x / (1.0f + __expf(-x));
}

// ---- gates lookup table: 1 wave per sample, lanes = neuron k ----
__global__ __launch_bounds__(256) void table_kernel(
    const float* __restrict__ fc_w1, const float* __restrict__ fc_b1,
    const float* __restrict__ fc_w2, const float* __restrict__ fc_b2,
    const float* __restrict__ fc_w3, const float* __restrict__ fc_b3,
    float4* __restrict__ table)
{
    __shared__ float s_h1[4][64];
    int tid = threadIdx.x;
    int s = tid >> 6;
    int k = tid & 63;
    int samp = blockIdx.x * 4 + s;
    float len = (float)samp * (1.0f / TBL_SCALE);

    float emb[16];
    const float inv_step = 17.0f / 5.0f;
    #pragma unroll
    for (int b = 0; b < 16; b++) {
        float d = len * inv_step - (float)(b + 1);
        emb[b] = __expf(-d * d) * 3.5714285714285716f; // 4/1.12
    }

    float acc = fc_b1[k];
    #pragma unroll
    for (int b = 0; b < 16; b++) acc = fmaf(emb[b], fc_w1[b * 64 + k], acc);
    s_h1[s][k] = silu(acc);
    __syncthreads();

    float acc2 = fc_b2[k];
    #pragma unroll
    for (int j = 0; j < 64; j++)
        acc2 = fmaf(s_h1[s][j], fc_w2[j * 64 + k], acc2);
    float h2 = silu(acc2);

    float p0 = h2 * fc_w3[k * 15 + 0];
    float p3 = h2 * fc_w3[k * 15 + 3];
    float p9 = h2 * fc_w3[k * 15 + 9];
    #pragma unroll
    for (int off = 32; off > 0; off >>= 1) {
        p0 += __shfl_down(p0, off, 64);
        p3 += __shfl_down(p3, off, 64);
        p9 += __shfl_down(p9, off, 64);
    }
    if (k == 0) {
        table[samp] = make_float4((fc_b3[0] + p0) * 0.125f,
                                  (fc_b3[3] + p3) * 0.125f,
                                  (fc_b3[9] + p9) * 0.125f, 0.0f);
    }
}

// ---- per-atom rows[10][8] and B[10][3][8][16]; one block per atom ----
__global__ __launch_bounds__(256) void rows_b_kernel(
    const float* __restrict__ emb_table,
    const float* __restrict__ w1, const float* __restrict__ b1,
    const float* __restrict__ w2, const float* __restrict__ b2,
    const float* __restrict__ tp_w,
    float* __restrict__ rows_g, float* __restrict__ B_g)
{
    __shared__ float s_r[8];
    int a = blockIdx.x;
    int tid = threadIdx.x;
    if (tid < 8) {
        float e[16];
        #pragma unroll
        for (int i = 0; i < 16; i++) e[i] = emb_table[a * 16 + i];
        float acc_j = b2[tid];
        for (int k = 0; k < 64; k++) {
            float acc = b1[k];
            #pragma unroll
            for (int i = 0; i < 16; i++) acc = fmaf(e[i], w1[i * 64 + k], acc);
            acc_j = fmaf(silu(acc), w2[k * 8 + tid], acc_j);
        }
        s_r[tid] = acc_j;
        rows_g[a * 8 + tid] = acc_j;
    }
    __syncthreads();
    for (int t = tid; t < 384; t += 256) {
        int pp = t >> 7, ub = (t >> 4) & 7, wb = t & 15;
        int P = (pp == 0) ? 0 : (pp == 1) ? 3 : 9;
        float acc = 0.0f;
        #pragma unroll
        for (int v = 0; v < 8; v++)
            acc = fmaf(s_r[v], tp_w[P * 1024 + (ub * 8 + v) * 16 + wb], acc);
        B_g[a * 384 + t] = acc;
    }
}

__global__ __launch_bounds__(256) void deg_kernel(
    const int* __restrict__ edge_dst, int* __restrict__ deg, int n_edges)
{
    int e = blockIdx.x * blockDim.x + threadIdx.x;
    if (e >= n_edges) return;
    atomicAdd(&deg[edge_dst[e]], 1);
}

__global__ __launch_bounds__(1024) void partial_kernel(
    const int* __restrict__ deg, int* __restrict__ bsum, int n)
{
    __shared__ int red[1024];
    int tid = threadIdx.x;
    int i = blockIdx.x * 1024 + tid;
    red[tid] = (i < n) ? deg[i] : 0;
    __syncthreads();
    #pragma unroll
    for (int off = 512; off > 0; off >>= 1) {
        if (tid < off) red[tid] += red[tid + off];
        __syncthreads();
    }
    if (tid == 0) bsum[blockIdx.x] = red[0];
}

__global__ __launch_bounds__(1024) void scan_write_kernel(
    const int* __restrict__ deg, const int* __restrict__ bsum,
    int* __restrict__ starts, int* __restrict__ cursor, int n, int nb)
{
    __shared__ int s[1024];
    __shared__ int sb[1024];
    int tid = threadIdx.x;

    sb[tid] = (tid < nb) ? bsum[tid] : 0;
    int i = blockIdx.x * 1024 + tid;
    int v = (i < n) ? deg[i] : 0;
    s[tid] = v;
    __syncthreads();
    #pragma unroll
    for (int off = 1; off < 1024; off <<= 1) {
        int t1 = (tid >= off) ? s[tid - off] : 0;
        int t2 = (tid >= off) ? sb[tid - off] : 0;
        __syncthreads();
        s[tid] += t1;
        sb[tid] += t2;
        __syncthreads();
    }
    int base = (blockIdx.x == 0) ? 0 : sb[blockIdx.x - 1];
    if (i < n) {
        int excl = base + s[tid] - v;
        starts[i] = excl;
        cursor[i] = excl;
    }
}

// ---- per-edge: geometry + table-lerp gates + 12-float record ----
// record: [G0, G1*Y1[0..2], G2*Y2[0..4], a_src, pad, pad]
__global__ __launch_bounds__(256) void edge_kernel(
    const float* __restrict__ pos,
    const int* __restrict__ A,
    const int* __restrict__ batch,
    const int* __restrict__ edge_src,
    const int* __restrict__ edge_dst,
    const float* __restrict__ edge_shifts,
    const float* __restrict__ cell,
    const float4* __restrict__ table,
    float* __restrict__ records,
    int* __restrict__ cursor,
    int n_edges)
{
    int e = blockIdx.x * blockDim.x + threadIdx.x;
    if (e >= n_edges) return;

    int src = edge_src[e];
    int dst = edge_dst[e];

    float sh0 = edge_shifts[3 * (size_t)e + 0];
    float sh1 = edge_shifts[3 * (size_t)e + 1];
    float sh2 = edge_shifts[3 * (size_t)e + 2];
    int g = batch[src];
    const float* C = cell + (size_t)g * 9;
    float shx = sh0 * C[0] + sh1 * C[3] + sh2 * C[6];
    float shy = sh0 * C[1] + sh1 * C[4] + sh2 * C[7];
    float shz = sh0 * C[2] + sh1 * C[5] + sh2 * C[8];

    float vx = pos[3 * (size_t)dst + 0] - pos[3 * (size_t)src + 0] + shx;
    float vy = pos[3 * (size_t)dst + 1] - pos[3 * (size_t)src + 1] + shy;
    float vz = pos[3 * (size_t)dst + 2] - pos[3 * (size_t)src + 2] + shz;

    float len = sqrtf(vx * vx + vy * vy + vz * vz);
    float invl = 1.0f / fmaxf(len, 1e-8f);
    float nx = vx * invl, ny = vy * invl, nz = vz * invl;

    float t = fminf(len * TBL_SCALE, (float)(TBL_N - 1));
    int i0 = (int)t;
    i0 = min(i0, TBL_N - 2);
    float fr = t - (float)i0;
    float4 T0 = table[i0];
    float4 T1 = table[i0 + 1];
    float g0 = fmaf(fr, T1.x - T0.x, T0.x);
    float g1 = fmaf(fr, T1.y - T0.y, T0.y);
    float g2 = fmaf(fr, T1.z - T0.z, T0.z);

    const float s3  = 1.7320508075688772f;
    const float s15 = 3.872983346207417f;
    const float s5  = 2.23606797749979f;
    float Y1_[3] = { s3 * ny, s3 * nz, s3 * nx };
    float Y2_[5] = { s15 * nx * ny, s15 * ny * nz,
                     0.5f * s5 * (3.0f * nz * nz - 1.0f),
                     s15 * nx * nz, 0.5f * s15 * (nx * nx - ny * ny) };

    int asrc = A[src];

    int slot = atomicAdd(&cursor[dst], 1);
    float4* r = (float4*)(records + (size_t)slot * 12);
    float4 r0 = { g0, g1 * Y1_[0], g1 * Y1_[1], g1 * Y1_[2] };
    float4 r1 = { g2 * Y2_[0], g2 * Y2_[1], g2 * Y2_[2], g2 * Y2_[3] };
    float4 r2 = { g2 * Y2_[4], __int_as_float(asrc), 0.0f, 0.0f };
    r[0] = r0; r[1] = r1; r[2] = r2;
}

// ---- one wave per node: streaming M-accumulate, per-atom B finish ----
__global__ __launch_bounds__(256) void gather_kernel(
    const float* __restrict__ records,
    const int* __restrict__ starts,
    const int* __restrict__ deg,
    const int* __restrict__ A,
    const float* __restrict__ rows_g,
    const float* __restrict__ B_g,
    float* __restrict__ out, int n_nodes, int n_atom)
{
    __shared__ float s_B[3840];      // [a][pp*128 + u*16 + w]
    __shared__ float s_rows[80];     // [a][u]
    __shared__ float s_M[4][80];     // per wave: [i'*8 + u], i' in 0..8

    int tid = threadIdx.x;
    int nB = n_atom * 384;
    for (int t = tid; t < nB; t += 256) s_B[t] = B_g[t];
    if (tid < n_atom * 8) s_rows[tid] = rows_g[tid];
    __syncthreads();

    int wv = tid >> 6;
    int lane = tid & 63;
    int node = blockIdx.x * 4 + wv;
    if (node >= n_nodes) return;

    int start = starts[node];
    int d = deg[node];
    int iq = lane >> 3, u = lane & 7;
    int anode = A[node];

    // phase 1: streaming M accumulation, unroll 4
    float m = 0.0f, m8 = 0.0f;
    const float* recs = records + (size_t)start * 12;
    int j = 0;
    for (; j + 4 <= d; j += 4) {
        const float* r0 = recs + (size_t)(j + 0) * 12;
        const float* r1 = recs + (size_t)(j + 1) * 12;
        const float* r2 = recs + (size_t)(j + 2) * 12;
        const float* r3 = recs + (size_t)(j + 3) * 12;
        float a0 = r0[iq], b0 = r0[8];
        float a1 = r1[iq], b1 = r1[8];
        float a2 = r2[iq], b2 = r2[8];
        float a3 = r3[iq], b3 = r3[8];
        float c0 = s_rows[__float_as_int(r0[9]) * 8 + u];
        float c1 = s_rows[__float_as_int(r1[9]) * 8 + u];
        float c2 = s_rows[__float_as_int(r2[9]) * 8 + u];
        float c3 = s_rows[__float_as_int(r3[9]) * 8 + u];
        m  = fmaf(a0, c0, m);  m8 = fmaf(b0, c0, m8);
        m  = fmaf(a1, c1, m);  m8 = fmaf(b1, c1, m8);
        m  = fmaf(a2, c2, m);  m8 = fmaf(b2, c2, m8);
        m  = fmaf(a3, c3, m);  m8 = fmaf(b3, c3, m8);
    }
    for (; j < d; j++) {
        const float* r0 = recs + (size_t)j * 12;
        float a0 = r0[iq], b0 = r0[8];
        float c0 = s_rows[__float_as_int(r0[9]) * 8 + u];
        m  = fmaf(a0, c0, m);
        m8 = fmaf(b0, c0, m8);
    }
    s_M[wv][iq * 8 + u] = m;
    if (lane < 8) s_M[wv][64 + u] = m8;

    // phase 2: 144 contractions of length 8 against per-atom B
    const float* Bn = s_B + anode * 384;
    float invd = 1.0f / fmaxf((float)d, 1.0f);
    float* row = out + (size_t)node * 144;
    {
        int c = lane;
        int pp, w, ip;
        if (c < 16) { pp = 0; w = c; ip = 0; }
        else { int t = c - 16; pp = 1; w = t / 3; ip = 1 + (t - 3 * (t / 3)); }
        float acc = 0.0f;
        #pragma unroll
        for (int uu = 0; uu < 8; uu++)
            acc = fmaf(Bn[pp * 128 + uu * 16 + w], s_M[wv][ip * 8 + uu], acc);
        row[c] = acc * invd;
    }
    {
        int t = lane;                      // c = 64 + lane
        int w = t / 5; int i = t - 5 * w;
        float acc = 0.0f;
        #pragma unroll
        for (int uu = 0; uu < 8; uu++)
            acc = fmaf(Bn[256 + uu * 16 + w], s_M[wv][(4 + i) * 8 + uu], acc);
        row[64 + lane] = acc * invd;
    }
    if (lane < 16) {
        int t = 64 + lane;                 // c = 128 + lane
        int w = t / 5; int i = t - 5 * w;
        float acc = 0.0f;
        #pragma unroll
        for (int uu = 0; uu < 8; uu++)
            acc = fmaf(Bn[256 + uu * 16 + w], s_M[wv][(4 + i) * 8 + uu], acc);
        row[128 + lane] = acc * invd;
    }
}

extern "C" void kernel_launch(void* const* d_in, const int* in_sizes, int n_in,
                              void* d_out, int out_size, void* d_ws, size_t ws_size,
                              hipStream_t stream)
{
    const float* pos         = (const float*)d_in[0];
    const int*   A           = (const int*)d_in[1];
    const int*   batch       = (const int*)d_in[2];
    const int*   edge_src    = (const int*)d_in[3];
    const int*   edge_dst    = (const int*)d_in[4];
    const float* edge_shifts = (const float*)d_in[5];
    const float* cell        = (const float*)d_in[6];
    const float* emb_table   = (const float*)d_in[7];
    const float* mlp_w1      = (const float*)d_in[8];
    const float* mlp_b1      = (const float*)d_in[9];
    const float* mlp_w2      = (const float*)d_in[10];
    const float* mlp_b2      = (const float*)d_in[11];
    const float* fc_w1       = (const float*)d_in[12];
    const float* fc_b1       = (const float*)d_in[13];
    const float* fc_w2       = (const float*)d_in[14];
    const float* fc_b2       = (const float*)d_in[15];
    const float* fc_w3       = (const float*)d_in[16];
    const float* fc_b3       = (const float*)d_in[17];
    const float* tp_w        = (const float*)d_in[18];

    int n_nodes = in_sizes[1];
    int n_edges = in_sizes[3];
    int n_atom  = in_sizes[7] / 16;
    int nb      = (n_nodes + 1023) / 1024;

    // ws layout
    float* table   = (float*)d_ws;                        // TBL_N*4 floats
    float* rows_g  = table + (size_t)TBL_N * 4;           // 128 (80 used)
    float* B_g     = rows_g + 128;                        // 3840
    int*   deg     = (int*)(B_g + 3840);                  // n_nodes
    int*   starts  = deg + n_nodes;                       // n_nodes
    int*   cursor  = starts + n_nodes;                    // n_nodes
    int*   bsum    = cursor + n_nodes;                    // 1024
    float* records = (float*)(bsum + 1024);               // n_edges*12

    hipMemsetAsync(deg, 0, (size_t)n_nodes * sizeof(int), stream);

    rows_b_kernel<<<n_atom, 256, 0, stream>>>(
        emb_table, mlp_w1, mlp_b1, mlp_w2, mlp_b2, tp_w, rows_g, B_g);

    table_kernel<<<TBL_N / 4, 256, 0, stream>>>(
        fc_w1, fc_b1, fc_w2, fc_b2, fc_w3, fc_b3, (float4*)table);

    deg_kernel<<<(n_edges + 255) / 256, 256, 0, stream>>>(edge_dst, deg, n_edges);

    partial_kernel<<<nb, 1024, 0, stream>>>(deg, bsum, n_nodes);

    scan_write_kernel<<<nb, 1024, 0, stream>>>(deg, bsum, starts, cursor,
                                               n_nodes, nb);

    edge_kernel<<<(n_edges + 255) / 256, 256, 0, stream>>>(
        pos, A, batch, edge_src, edge_dst, edge_shifts, cell,
        (const float4*)table, records, cursor, n_edges);

    gather_kernel<<<(n_nodes + 3) / 4, 256, 0, stream>>>(
        records, starts, deg, A, rows_g, B_g, (float*)d_out, n_nodes, n_atom);
}

// Round 8
// 130.750 us; speedup vs baseline: 28.7359x; 1.0007x over previous
//
#include <hip/hip_runtime.h>
#include <cstddef>

// ICTDIrrepsE3Conv — round 8.
//  - gates = f(edge_length) only -> 8192-entry lerp table (wave-parallel build)
//  - atom-type factorization: rows[10][8] and B[10][3][8][16] precomputed
//  - CSR gather: streaming M accumulation + per-atom B finish
//  - multi-block CSR scan
//  - NEW: custom zero_kernel replaces hipMemsetAsync's fillBufferAligned,
//    which ran 43 us (!) for a 160 KB clear and topped round 7's profile.

#define TBL_N 8192
#define TBL_SCALE 1024.0f   // TBL_N / 8.0 range

__device__ __forceinline__ float silu(float x) {
    return x / (1.0f + __expf(-x));
}

// ---- grid-stride int4 zero fill ----
__global__ __launch_bounds__(256) void zero_kernel(int4* __restrict__ p, int n4)
{
    int i = blockIdx.x * blockDim.x + threadIdx.x;
    if (i < n4) p[i] = make_int4(0, 0, 0, 0);
}

// ---- gates lookup table: 1 wave per sample, lanes = neuron k ----
__global__ __launch_bounds__(256) void table_kernel(
    const float* __restrict__ fc_w1, const float* __restrict__ fc_b1,
    const float* __restrict__ fc_w2, const float* __restrict__ fc_b2,
    const float* __restrict__ fc_w3, const float* __restrict__ fc_b3,
    float4* __restrict__ table)
{
    __shared__ float s_h1[4][64];
    int tid = threadIdx.x;
    int s = tid >> 6;
    int k = tid & 63;
    int samp = blockIdx.x * 4 + s;
    float len = (float)samp * (1.0f / TBL_SCALE);

    float emb[16];
    const float inv_step = 17.0f / 5.0f;
    #pragma unroll
    for (int b = 0; b < 16; b++) {
        float d = len * inv_step - (float)(b + 1);
        emb[b] = __expf(-d * d) * 3.5714285714285716f; // 4/1.12
    }

    float acc = fc_b1[k];
    #pragma unroll
    for (int b = 0; b < 16; b++) acc = fmaf(emb[b], fc_w1[b * 64 + k], acc);
    s_h1[s][k] = silu(acc);
    __syncthreads();

    float acc2 = fc_b2[k];
    #pragma unroll
    for (int j = 0; j < 64; j++)
        acc2 = fmaf(s_h1[s][j], fc_w2[j * 64 + k], acc2);
    float h2 = silu(acc2);

    float p0 = h2 * fc_w3[k * 15 + 0];
    float p3 = h2 * fc_w3[k * 15 + 3];
    float p9 = h2 * fc_w3[k * 15 + 9];
    #pragma unroll
    for (int off = 32; off > 0; off >>= 1) {
        p0 += __shfl_down(p0, off, 64);
        p3 += __shfl_down(p3, off, 64);
        p9 += __shfl_down(p9, off, 64);
    }
    if (k == 0) {
        table[samp] = make_float4((fc_b3[0] + p0) * 0.125f,
                                  (fc_b3[3] + p3) * 0.125f,
                                  (fc_b3[9] + p9) * 0.125f, 0.0f);
    }
}

// ---- per-atom rows[10][8] and B[10][3][8][16]; one block per atom ----
__global__ __launch_bounds__(256) void rows_b_kernel(
    const float* __restrict__ emb_table,
    const float* __restrict__ w1, const float* __restrict__ b1,
    const float* __restrict__ w2, const float* __restrict__ b2,
    const float* __restrict__ tp_w,
    float* __restrict__ rows_g, float* __restrict__ B_g)
{
    __shared__ float s_r[8];
    int a = blockIdx.x;
    int tid = threadIdx.x;
    if (tid < 8) {
        float e[16];
        #pragma unroll
        for (int i = 0; i < 16; i++) e[i] = emb_table[a * 16 + i];
        float acc_j = b2[tid];
        for (int k = 0; k < 64; k++) {
            float acc = b1[k];
            #pragma unroll
            for (int i = 0; i < 16; i++) acc = fmaf(e[i], w1[i * 64 + k], acc);
            acc_j = fmaf(silu(acc), w2[k * 8 + tid], acc_j);
        }
        s_r[tid] = acc_j;
        rows_g[a * 8 + tid] = acc_j;
    }
    __syncthreads();
    for (int t = tid; t < 384; t += 256) {
        int pp = t >> 7, ub = (t >> 4) & 7, wb = t & 15;
        int P = (pp == 0) ? 0 : (pp == 1) ? 3 : 9;
        float acc = 0.0f;
        #pragma unroll
        for (int v = 0; v < 8; v++)
            acc = fmaf(s_r[v], tp_w[P * 1024 + (ub * 8 + v) * 16 + wb], acc);
        B_g[a * 384 + t] = acc;
    }
}

__global__ __launch_bounds__(256) void deg_kernel(
    const int* __restrict__ edge_dst, int* __restrict__ deg, int n_edges)
{
    int e = blockIdx.x * blockDim.x + threadIdx.x;
    if (e >= n_edges) return;
    atomicAdd(&deg[edge_dst[e]], 1);
}

__global__ __launch_bounds__(1024) void partial_kernel(
    const int* __restrict__ deg, int* __restrict__ bsum, int n)
{
    __shared__ int red[1024];
    int tid = threadIdx.x;
    int i = blockIdx.x * 1024 + tid;
    red[tid] = (i < n) ? deg[i] : 0;
    __syncthreads();
    #pragma unroll
    for (int off = 512; off > 0; off >>= 1) {
        if (tid < off) red[tid] += red[tid + off];
        __syncthreads();
    }
    if (tid == 0) bsum[blockIdx.x] = red[0];
}

__global__ __launch_bounds__(1024) void scan_write_kernel(
    const int* __restrict__ deg, const int* __restrict__ bsum,
    int* __restrict__ starts, int* __restrict__ cursor, int n, int nb)
{
    __shared__ int s[1024];
    __shared__ int sb[1024];
    int tid = threadIdx.x;

    sb[tid] = (tid < nb) ? bsum[tid] : 0;
    int i = blockIdx.x * 1024 + tid;
    int v = (i < n) ? deg[i] : 0;
    s[tid] = v;
    __syncthreads();
    #pragma unroll
    for (int off = 1; off < 1024; off <<= 1) {
        int t1 = (tid >= off) ? s[tid - off] : 0;
        int t2 = (tid >= off) ? sb[tid - off] : 0;
        __syncthreads();
        s[tid] += t1;
        sb[tid] += t2;
        __syncthreads();
    }
    int base = (blockIdx.x == 0) ? 0 : sb[blockIdx.x - 1];
    if (i < n) {
        int excl = base + s[tid] - v;
        starts[i] = excl;
        cursor[i] = excl;
    }
}

// ---- per-edge: geometry + table-lerp gates + 12-float record ----
// record: [G0, G1*Y1[0..2], G2*Y2[0..4], a_src, pad, pad]
__global__ __launch_bounds__(256) void edge_kernel(
    const float* __restrict__ pos,
    const int* __restrict__ A,
    const int* __restrict__ batch,
    const int* __restrict__ edge_src,
    const int* __restrict__ edge_dst,
    const float* __restrict__ edge_shifts,
    const float* __restrict__ cell,
    const float4* __restrict__ table,
    float* __restrict__ records,
    int* __restrict__ cursor,
    int n_edges)
{
    int e = blockIdx.x * blockDim.x + threadIdx.x;
    if (e >= n_edges) return;

    int src = edge_src[e];
    int dst = edge_dst[e];

    float sh0 = edge_shifts[3 * (size_t)e + 0];
    float sh1 = edge_shifts[3 * (size_t)e + 1];
    float sh2 = edge_shifts[3 * (size_t)e + 2];
    int g = batch[src];
    const float* C = cell + (size_t)g * 9;
    float shx = sh0 * C[0] + sh1 * C[3] + sh2 * C[6];
    float shy = sh0 * C[1] + sh1 * C[4] + sh2 * C[7];
    float shz = sh0 * C[2] + sh1 * C[5] + sh2 * C[8];

    float vx = pos[3 * (size_t)dst + 0] - pos[3 * (size_t)src + 0] + shx;
    float vy = pos[3 * (size_t)dst + 1] - pos[3 * (size_t)src + 1] + shy;
    float vz = pos[3 * (size_t)dst + 2] - pos[3 * (size_t)src + 2] + shz;

    float len = sqrtf(vx * vx + vy * vy + vz * vz);
    float invl = 1.0f / fmaxf(len, 1e-8f);
    float nx = vx * invl, ny = vy * invl, nz = vz * invl;

    float t = fminf(len * TBL_SCALE, (float)(TBL_N - 1));
    int i0 = (int)t;
    i0 = min(i0, TBL_N - 2);
    float fr = t - (float)i0;
    float4 T0 = table[i0];
    float4 T1 = table[i0 + 1];
    float g0 = fmaf(fr, T1.x - T0.x, T0.x);
    float g1 = fmaf(fr, T1.y - T0.y, T0.y);
    float g2 = fmaf(fr, T1.z - T0.z, T0.z);

    const float s3  = 1.7320508075688772f;
    const float s15 = 3.872983346207417f;
    const float s5  = 2.23606797749979f;
    float Y1_[3] = { s3 * ny, s3 * nz, s3 * nx };
    float Y2_[5] = { s15 * nx * ny, s15 * ny * nz,
                     0.5f * s5 * (3.0f * nz * nz - 1.0f),
                     s15 * nx * nz, 0.5f * s15 * (nx * nx - ny * ny) };

    int asrc = A[src];

    int slot = atomicAdd(&cursor[dst], 1);
    float4* r = (float4*)(records + (size_t)slot * 12);
    float4 r0 = { g0, g1 * Y1_[0], g1 * Y1_[1], g1 * Y1_[2] };
    float4 r1 = { g2 * Y2_[0], g2 * Y2_[1], g2 * Y2_[2], g2 * Y2_[3] };
    float4 r2 = { g2 * Y2_[4], __int_as_float(asrc), 0.0f, 0.0f };
    r[0] = r0; r[1] = r1; r[2] = r2;
}

// ---- one wave per node: streaming M-accumulate, per-atom B finish ----
__global__ __launch_bounds__(256) void gather_kernel(
    const float* __restrict__ records,
    const int* __restrict__ starts,
    const int* __restrict__ deg,
    const int* __restrict__ A,
    const float* __restrict__ rows_g,
    const float* __restrict__ B_g,
    float* __restrict__ out, int n_nodes, int n_atom)
{
    __shared__ float s_B[3840];      // [a][pp*128 + u*16 + w]
    __shared__ float s_rows[80];     // [a][u]
    __shared__ float s_M[4][80];     // per wave: [i'*8 + u], i' in 0..8

    int tid = threadIdx.x;
    int nB = n_atom * 384;
    for (int t = tid; t < nB; t += 256) s_B[t] = B_g[t];
    if (tid < n_atom * 8) s_rows[tid] = rows_g[tid];
    __syncthreads();

    int wv = tid >> 6;
    int lane = tid & 63;
    int node = blockIdx.x * 4 + wv;
    if (node >= n_nodes) return;

    int start = starts[node];
    int d = deg[node];
    int iq = lane >> 3, u = lane & 7;
    int anode = A[node];

    // phase 1: streaming M accumulation, unroll 4
    float m = 0.0f, m8 = 0.0f;
    const float* recs = records + (size_t)start * 12;
    int j = 0;
    for (; j + 4 <= d; j += 4) {
        const float* r0 = recs + (size_t)(j + 0) * 12;
        const float* r1 = recs + (size_t)(j + 1) * 12;
        const float* r2 = recs + (size_t)(j + 2) * 12;
        const float* r3 = recs + (size_t)(j + 3) * 12;
        float a0 = r0[iq], b0 = r0[8];
        float a1 = r1[iq], b1 = r1[8];
        float a2 = r2[iq], b2 = r2[8];
        float a3 = r3[iq], b3 = r3[8];
        float c0 = s_rows[__float_as_int(r0[9]) * 8 + u];
        float c1 = s_rows[__float_as_int(r1[9]) * 8 + u];
        float c2 = s_rows[__float_as_int(r2[9]) * 8 + u];
        float c3 = s_rows[__float_as_int(r3[9]) * 8 + u];
        m  = fmaf(a0, c0, m);  m8 = fmaf(b0, c0, m8);
        m  = fmaf(a1, c1, m);  m8 = fmaf(b1, c1, m8);
        m  = fmaf(a2, c2, m);  m8 = fmaf(b2, c2, m8);
        m  = fmaf(a3, c3, m);  m8 = fmaf(b3, c3, m8);
    }
    for (; j < d; j++) {
        const float* r0 = recs + (size_t)j * 12;
        float a0 = r0[iq], b0 = r0[8];
        float c0 = s_rows[__float_as_int(r0[9]) * 8 + u];
        m  = fmaf(a0, c0, m);
        m8 = fmaf(b0, c0, m8);
    }
    s_M[wv][iq * 8 + u] = m;
    if (lane < 8) s_M[wv][64 + u] = m8;

    // phase 2: 144 contractions of length 8 against per-atom B
    const float* Bn = s_B + anode * 384;
    float invd = 1.0f / fmaxf((float)d, 1.0f);
    float* row = out + (size_t)node * 144;
    {
        int c = lane;
        int pp, w, ip;
        if (c < 16) { pp = 0; w = c; ip = 0; }
        else { int t = c - 16; pp = 1; w = t / 3; ip = 1 + (t - 3 * (t / 3)); }
        float acc = 0.0f;
        #pragma unroll
        for (int uu = 0; uu < 8; uu++)
            acc = fmaf(Bn[pp * 128 + uu * 16 + w], s_M[wv][ip * 8 + uu], acc);
        row[c] = acc * invd;
    }
    {
        int t = lane;                      // c = 64 + lane
        int w = t / 5; int i = t - 5 * w;
        float acc = 0.0f;
        #pragma unroll
        for (int uu = 0; uu < 8; uu++)
            acc = fmaf(Bn[256 + uu * 16 + w], s_M[wv][(4 + i) * 8 + uu], acc);
        row[64 + lane] = acc * invd;
    }
    if (lane < 16) {
        int t = 64 + lane;                 // c = 128 + lane
        int w = t / 5; int i = t - 5 * w;
        float acc = 0.0f;
        #pragma unroll
        for (int uu = 0; uu < 8; uu++)
            acc = fmaf(Bn[256 + uu * 16 + w], s_M[wv][(4 + i) * 8 + uu], acc);
        row[128 + lane] = acc * invd;
    }
}

extern "C" void kernel_launch(void* const* d_in, const int* in_sizes, int n_in,
                              void* d_out, int out_size, void* d_ws, size_t ws_size,
                              hipStream_t stream)
{
    const float* pos         = (const float*)d_in[0];
    const int*   A           = (const int*)d_in[1];
    const int*   batch       = (const int*)d_in[2];
    const int*   edge_src    = (const int*)d_in[3];
    const int*   edge_dst    = (const int*)d_in[4];
    const float* edge_shifts = (const float*)d_in[5];
    const float* cell        = (const float*)d_in[6];
    const float* emb_table   = (const float*)d_in[7];
    const float* mlp_w1      = (const float*)d_in[8];
    const float* mlp_b1      = (const float*)d_in[9];
    const float* mlp_w2      = (const float*)d_in[10];
    const float* mlp_b2      = (const float*)d_in[11];
    const float* fc_w1       = (const float*)d_in[12];
    const float* fc_b1       = (const float*)d_in[13];
    const float* fc_w2       = (const float*)d_in[14];
    const float* fc_b2       = (const float*)d_in[15];
    const float* fc_w3       = (const float*)d_in[16];
    const float* fc_b3       = (const float*)d_in[17];
    const float* tp_w        = (const float*)d_in[18];

    int n_nodes = in_sizes[1];
    int n_edges = in_sizes[3];
    int n_atom  = in_sizes[7] / 16;
    int nb      = (n_nodes + 1023) / 1024;

    // ws layout (deg 16B-aligned: table/rows/B are multiples of 4 floats)
    float* table   = (float*)d_ws;                        // TBL_N*4 floats
    float* rows_g  = table + (size_t)TBL_N * 4;           // 128 (80 used)
    float* B_g     = rows_g + 128;                        // 3840
    int*   deg     = (int*)(B_g + 3840);                  // n_nodes
    int*   starts  = deg + n_nodes;                       // n_nodes
    int*   cursor  = starts + n_nodes;                    // n_nodes
    int*   bsum    = cursor + n_nodes;                    // 1024
    float* records = (float*)(bsum + 1024);               // n_edges*12

    int n4 = (n_nodes + 3) / 4;   // n_nodes=40000 -> exact int4 fill
    zero_kernel<<<(n4 + 255) / 256, 256, 0, stream>>>((int4*)deg, n4);

    rows_b_kernel<<<n_atom, 256, 0, stream>>>(
        emb_table, mlp_w1, mlp_b1, mlp_w2, mlp_b2, tp_w, rows_g, B_g);

    table_kernel<<<TBL_N / 4, 256, 0, stream>>>(
        fc_w1, fc_b1, fc_w2, fc_b2, fc_w3, fc_b3, (float4*)table);

    deg_kernel<<<(n_edges + 255) / 256, 256, 0, stream>>>(edge_dst, deg, n_edges);

    partial_kernel<<<nb, 1024, 0, stream>>>(deg, bsum, n_nodes);

    scan_write_kernel<<<nb, 1024, 0, stream>>>(deg, bsum, starts, cursor,
                                               n_nodes, nb);

    edge_kernel<<<(n_edges + 255) / 256, 256, 0, stream>>>(
        pos, A, batch, edge_src, edge_dst, edge_shifts, cell,
        (const float4*)table, records, cursor, n_edges);

    gather_kernel<<<(n_nodes + 3) / 4, 256, 0, stream>>>(
        records, starts, deg, A, rows_g, B_g, (float*)d_out, n_nodes, n_atom);
}

// Round 9
// 112.809 us; speedup vs baseline: 33.3062x; 1.1590x over previous
//
#include <hip/hip_runtime.h>
#include <cstddef>

// ICTDIrrepsE3Conv — round 9.
//  - gates = f(edge_length) only -> 8192-entry lerp table
//  - atom-type factorization: rows[10][8], B[10][3][8][16] precomputed
//  - CSR gather, streaming M accumulation + per-atom B finish
//  - NEW: setup_kernel fuses {zero deg, rows_b, table} (8 -> 6 launches)
//  - NEW: record = 20 floats of interleaved (G_iq, G8) float2 pairs + asrc
//    -> gather hot loop does 2 loads/edge (float2 + asrc) instead of 3
//  NOTE: the 44 us fillBufferAligned dispatches in the profile are the
//  harness's 256 MiB workspace poison fills, not ours (round 7->8 A/B:
//  removing our memset changed nothing).

#define TBL_N 8192
#define TBL_SCALE 1024.0f   // TBL_N / 8.0 range

__device__ __forceinline__ float silu(float x) {
    return x / (1.0f + __expf(-x));
}

// ---- fused setup: blocks [0,zb) zero deg; [zb,zb+n_atom) rows+B;
//      [zb+n_atom, zb+n_atom+TBL_N/4) table ----
__global__ __launch_bounds__(256) void setup_kernel(
    const float* __restrict__ emb_table,
    const float* __restrict__ w1, const float* __restrict__ b1,
    const float* __restrict__ w2, const float* __restrict__ b2,
    const float* __restrict__ tp_w,
    const float* __restrict__ fc_w1, const float* __restrict__ fc_b1,
    const float* __restrict__ fc_w2, const float* __restrict__ fc_b2,
    const float* __restrict__ fc_w3, const float* __restrict__ fc_b3,
    float* __restrict__ rows_g, float* __restrict__ B_g,
    float4* __restrict__ table,
    int4* __restrict__ deg4, int n4, int zb, int n_atom)
{
    int bid = blockIdx.x;
    int tid = threadIdx.x;

    if (bid < zb) {
        int i = bid * 256 + tid;
        if (i < n4) deg4[i] = make_int4(0, 0, 0, 0);
        return;
    }
    if (bid < zb + n_atom) {
        // rows + B for atom a
        __shared__ float s_r[8];
        int a = bid - zb;
        if (tid < 8) {
            float e[16];
            #pragma unroll
            for (int i = 0; i < 16; i++) e[i] = emb_table[a * 16 + i];
            float acc_j = b2[tid];
            for (int k = 0; k < 64; k++) {
                float acc = b1[k];
                #pragma unroll
                for (int i = 0; i < 16; i++) acc = fmaf(e[i], w1[i * 64 + k], acc);
                acc_j = fmaf(silu(acc), w2[k * 8 + tid], acc_j);
            }
            s_r[tid] = acc_j;
            rows_g[a * 8 + tid] = acc_j;
        }
        __syncthreads();
        for (int t = tid; t < 384; t += 256) {
            int pp = t >> 7, ub = (t >> 4) & 7, wb = t & 15;
            int P = (pp == 0) ? 0 : (pp == 1) ? 3 : 9;
            float acc = 0.0f;
            #pragma unroll
            for (int v = 0; v < 8; v++)
                acc = fmaf(s_r[v], tp_w[P * 1024 + (ub * 8 + v) * 16 + wb], acc);
            B_g[a * 384 + t] = acc;
        }
        return;
    }

    // table: 4 samples per block, 1 wave per sample
    __shared__ float s_h1[4][64];
    int tb = bid - zb - n_atom;
    int s = tid >> 6;
    int k = tid & 63;
    int samp = tb * 4 + s;
    float len = (float)samp * (1.0f / TBL_SCALE);

    float emb[16];
    const float inv_step = 17.0f / 5.0f;
    #pragma unroll
    for (int b = 0; b < 16; b++) {
        float d = len * inv_step - (float)(b + 1);
        emb[b] = __expf(-d * d) * 3.5714285714285716f; // 4/1.12
    }

    float acc = fc_b1[k];
    #pragma unroll
    for (int b = 0; b < 16; b++) acc = fmaf(emb[b], fc_w1[b * 64 + k], acc);
    s_h1[s][k] = silu(acc);
    __syncthreads();

    float acc2 = fc_b2[k];
    #pragma unroll
    for (int j = 0; j < 64; j++)
        acc2 = fmaf(s_h1[s][j], fc_w2[j * 64 + k], acc2);
    float h2 = silu(acc2);

    float p0 = h2 * fc_w3[k * 15 + 0];
    float p3 = h2 * fc_w3[k * 15 + 3];
    float p9 = h2 * fc_w3[k * 15 + 9];
    #pragma unroll
    for (int off = 32; off > 0; off >>= 1) {
        p0 += __shfl_down(p0, off, 64);
        p3 += __shfl_down(p3, off, 64);
        p9 += __shfl_down(p9, off, 64);
    }
    if (k == 0) {
        table[samp] = make_float4((fc_b3[0] + p0) * 0.125f,
                                  (fc_b3[3] + p3) * 0.125f,
                                  (fc_b3[9] + p9) * 0.125f, 0.0f);
    }
}

__global__ __launch_bounds__(256) void deg_kernel(
    const int* __restrict__ edge_dst, int* __restrict__ deg, int n_edges)
{
    int e = blockIdx.x * blockDim.x + threadIdx.x;
    if (e >= n_edges) return;
    atomicAdd(&deg[edge_dst[e]], 1);
}

__global__ __launch_bounds__(1024) void partial_kernel(
    const int* __restrict__ deg, int* __restrict__ bsum, int n)
{
    __shared__ int red[1024];
    int tid = threadIdx.x;
    int i = blockIdx.x * 1024 + tid;
    red[tid] = (i < n) ? deg[i] : 0;
    __syncthreads();
    #pragma unroll
    for (int off = 512; off > 0; off >>= 1) {
        if (tid < off) red[tid] += red[tid + off];
        __syncthreads();
    }
    if (tid == 0) bsum[blockIdx.x] = red[0];
}

__global__ __launch_bounds__(1024) void scan_write_kernel(
    const int* __restrict__ deg, const int* __restrict__ bsum,
    int* __restrict__ starts, int* __restrict__ cursor, int n, int nb)
{
    __shared__ int s[1024];
    __shared__ int sb[1024];
    int tid = threadIdx.x;

    sb[tid] = (tid < nb) ? bsum[tid] : 0;
    int i = blockIdx.x * 1024 + tid;
    int v = (i < n) ? deg[i] : 0;
    s[tid] = v;
    __syncthreads();
    #pragma unroll
    for (int off = 1; off < 1024; off <<= 1) {
        int t1 = (tid >= off) ? s[tid - off] : 0;
        int t2 = (tid >= off) ? sb[tid - off] : 0;
        __syncthreads();
        s[tid] += t1;
        sb[tid] += t2;
        __syncthreads();
    }
    int base = (blockIdx.x == 0) ? 0 : sb[blockIdx.x - 1];
    if (i < n) {
        int excl = base + s[tid] - v;
        starts[i] = excl;
        cursor[i] = excl;
    }
}

// ---- per-edge: geometry + table-lerp gates + 20-float record ----
// record layout (floats): [ (G0,G8),(G1,G8),...,(G7,G8), asrc, pad,pad,pad ]
// where G0=g0, G1..3=g1*Y1, G4..8=g2*Y2.
__global__ __launch_bounds__(256) void edge_kernel(
    const float* __restrict__ pos,
    const int* __restrict__ A,
    const int* __restrict__ batch,
    const int* __restrict__ edge_src,
    const int* __restrict__ edge_dst,
    const float* __restrict__ edge_shifts,
    const float* __restrict__ cell,
    const float4* __restrict__ table,
    float* __restrict__ records,
    int* __restrict__ cursor,
    int n_edges)
{
    int e = blockIdx.x * blockDim.x + threadIdx.x;
    if (e >= n_edges) return;

    int src = edge_src[e];
    int dst = edge_dst[e];

    float sh0 = edge_shifts[3 * (size_t)e + 0];
    float sh1 = edge_shifts[3 * (size_t)e + 1];
    float sh2 = edge_shifts[3 * (size_t)e + 2];
    int g = batch[src];
    const float* C = cell + (size_t)g * 9;
    float shx = sh0 * C[0] + sh1 * C[3] + sh2 * C[6];
    float shy = sh0 * C[1] + sh1 * C[4] + sh2 * C[7];
    float shz = sh0 * C[2] + sh1 * C[5] + sh2 * C[8];

    float vx = pos[3 * (size_t)dst + 0] - pos[3 * (size_t)src + 0] + shx;
    float vy = pos[3 * (size_t)dst + 1] - pos[3 * (size_t)src + 1] + shy;
    float vz = pos[3 * (size_t)dst + 2] - pos[3 * (size_t)src + 2] + shz;

    float len = sqrtf(vx * vx + vy * vy + vz * vz);
    float invl = 1.0f / fmaxf(len, 1e-8f);
    float nx = vx * invl, ny = vy * invl, nz = vz * invl;

    float t = fminf(len * TBL_SCALE, (float)(TBL_N - 1));
    int i0 = (int)t;
    i0 = min(i0, TBL_N - 2);
    float fr = t - (float)i0;
    float4 T0 = table[i0];
    float4 T1 = table[i0 + 1];
    float g0 = fmaf(fr, T1.x - T0.x, T0.x);
    float g1 = fmaf(fr, T1.y - T0.y, T0.y);
    float g2 = fmaf(fr, T1.z - T0.z, T0.z);

    const float s3  = 1.7320508075688772f;
    const float s15 = 3.872983346207417f;
    const float s5  = 2.23606797749979f;
    float G1x = g1 * s3 * ny, G1y = g1 * s3 * nz, G1z = g1 * s3 * nx;
    float G4 = g2 * s15 * nx * ny;
    float G5 = g2 * s15 * ny * nz;
    float G6 = g2 * 0.5f * s5 * (3.0f * nz * nz - 1.0f);
    float G7 = g2 * s15 * nx * nz;
    float G8 = g2 * 0.5f * s15 * (nx * nx - ny * ny);

    int asrc = A[src];

    int slot = atomicAdd(&cursor[dst], 1);
    float4* r = (float4*)(records + (size_t)slot * 20);
    r[0] = make_float4(g0,  G8, G1x, G8);
    r[1] = make_float4(G1y, G8, G1z, G8);
    r[2] = make_float4(G4,  G8, G5,  G8);
    r[3] = make_float4(G6,  G8, G7,  G8);
    r[4] = make_float4(__int_as_float(asrc), 0.0f, 0.0f, 0.0f);
}

// ---- one wave per node: streaming M-accumulate, per-atom B finish ----
__global__ __launch_bounds__(256) void gather_kernel(
    const float* __restrict__ records,
    const int* __restrict__ starts,
    const int* __restrict__ deg,
    const int* __restrict__ A,
    const float* __restrict__ rows_g,
    const float* __restrict__ B_g,
    float* __restrict__ out, int n_nodes, int n_atom)
{
    __shared__ float s_B[3840];      // [a][pp*128 + u*16 + w]
    __shared__ float s_rows[80];     // [a][u]
    __shared__ float s_M[4][80];     // per wave: [i'*8 + u], i' in 0..8

    int tid = threadIdx.x;
    {
        float4* dB = (float4*)s_B;
        const float4* sB = (const float4*)B_g;
        int nB4 = n_atom * 96;
        for (int t = tid; t < nB4; t += 256) dB[t] = sB[t];
        if (tid < n_atom * 8) s_rows[tid] = rows_g[tid];
    }
    __syncthreads();

    int wv = tid >> 6;
    int lane = tid & 63;
    int node = blockIdx.x * 4 + wv;
    if (node >= n_nodes) return;

    int start = starts[node];
    int d = deg[node];
    int iq = lane >> 3, u = lane & 7;
    int anode = A[node];

    // phase 1: streaming M accumulation; 2 loads per edge (pair + asrc)
    float m = 0.0f, m8 = 0.0f;
    const float* recs = records + (size_t)start * 20;
    int j = 0;
    for (; j + 4 <= d; j += 4) {
        const float* r0 = recs + (size_t)(j + 0) * 20;
        const float* r1 = recs + (size_t)(j + 1) * 20;
        const float* r2 = recs + (size_t)(j + 2) * 20;
        const float* r3 = recs + (size_t)(j + 3) * 20;
        float2 p0 = *(const float2*)(r0 + 2 * iq);
        float2 p1 = *(const float2*)(r1 + 2 * iq);
        float2 p2 = *(const float2*)(r2 + 2 * iq);
        float2 p3 = *(const float2*)(r3 + 2 * iq);
        float c0 = s_rows[__float_as_int(r0[16]) * 8 + u];
        float c1 = s_rows[__float_as_int(r1[16]) * 8 + u];
        float c2 = s_rows[__float_as_int(r2[16]) * 8 + u];
        float c3 = s_rows[__float_as_int(r3[16]) * 8 + u];
        m  = fmaf(p0.x, c0, m);  m8 = fmaf(p0.y, c0, m8);
        m  = fmaf(p1.x, c1, m);  m8 = fmaf(p1.y, c1, m8);
        m  = fmaf(p2.x, c2, m);  m8 = fmaf(p2.y, c2, m8);
        m  = fmaf(p3.x, c3, m);  m8 = fmaf(p3.y, c3, m8);
    }
    for (; j < d; j++) {
        const float* r0 = recs + (size_t)j * 20;
        float2 p0 = *(const float2*)(r0 + 2 * iq);
        float c0 = s_rows[__float_as_int(r0[16]) * 8 + u];
        m  = fmaf(p0.x, c0, m);
        m8 = fmaf(p0.y, c0, m8);
    }
    s_M[wv][iq * 8 + u] = m;
    if (lane < 8) s_M[wv][64 + u] = m8;   // only iq==0 lanes' m8 consumed

    // phase 2: 144 contractions of length 8 against per-atom B
    const float* Bn = s_B + anode * 384;
    float invd = 1.0f / fmaxf((float)d, 1.0f);
    float* row = out + (size_t)node * 144;
    {
        int c = lane;
        int pp, w, ip;
        if (c < 16) { pp = 0; w = c; ip = 0; }
        else { int t = c - 16; pp = 1; w = t / 3; ip = 1 + (t - 3 * (t / 3)); }
        float acc = 0.0f;
        #pragma unroll
        for (int uu = 0; uu < 8; uu++)
            acc = fmaf(Bn[pp * 128 + uu * 16 + w], s_M[wv][ip * 8 + uu], acc);
        row[c] = acc * invd;
    }
    {
        int t = lane;                      // c = 64 + lane
        int w = t / 5; int i = t - 5 * w;
        float acc = 0.0f;
        #pragma unroll
        for (int uu = 0; uu < 8; uu++)
            acc = fmaf(Bn[256 + uu * 16 + w], s_M[wv][(4 + i) * 8 + uu], acc);
        row[64 + lane] = acc * invd;
    }
    if (lane < 16) {
        int t = 64 + lane;                 // c = 128 + lane
        int w = t / 5; int i = t - 5 * w;
        float acc = 0.0f;
        #pragma unroll
        for (int uu = 0; uu < 8; uu++)
            acc = fmaf(Bn[256 + uu * 16 + w], s_M[wv][(4 + i) * 8 + uu], acc);
        row[128 + lane] = acc * invd;
    }
}

extern "C" void kernel_launch(void* const* d_in, const int* in_sizes, int n_in,
                              void* d_out, int out_size, void* d_ws, size_t ws_size,
                              hipStream_t stream)
{
    const float* pos         = (const float*)d_in[0];
    const int*   A           = (const int*)d_in[1];
    const int*   batch       = (const int*)d_in[2];
    const int*   edge_src    = (const int*)d_in[3];
    const int*   edge_dst    = (const int*)d_in[4];
    const float* edge_shifts = (const float*)d_in[5];
    const float* cell        = (const float*)d_in[6];
    const float* emb_table   = (const float*)d_in[7];
    const float* mlp_w1      = (const float*)d_in[8];
    const float* mlp_b1      = (const float*)d_in[9];
    const float* mlp_w2      = (const float*)d_in[10];
    const float* mlp_b2      = (const float*)d_in[11];
    const float* fc_w1       = (const float*)d_in[12];
    const float* fc_b1       = (const float*)d_in[13];
    const float* fc_w2       = (const float*)d_in[14];
    const float* fc_b2       = (const float*)d_in[15];
    const float* fc_w3       = (const float*)d_in[16];
    const float* fc_b3       = (const float*)d_in[17];
    const float* tp_w        = (const float*)d_in[18];

    int n_nodes = in_sizes[1];
    int n_edges = in_sizes[3];
    int n_atom  = in_sizes[7] / 16;
    int nb      = (n_nodes + 1023) / 1024;

    // ws layout
    float* table   = (float*)d_ws;                        // TBL_N*4 floats
    float* rows_g  = table + (size_t)TBL_N * 4;           // 128 (80 used)
    float* B_g     = rows_g + 128;                        // 3840
    int*   deg     = (int*)(B_g + 3840);                  // n_nodes
    int*   starts  = deg + n_nodes;                       // n_nodes
    int*   cursor  = starts + n_nodes;                    // n_nodes
    int*   bsum    = cursor + n_nodes;                    // 1024
    float* records = (float*)(bsum + 1024);               // n_edges*20

    int n4 = (n_nodes + 3) / 4;
    int zb = (n4 + 255) / 256;

    setup_kernel<<<zb + n_atom + TBL_N / 4, 256, 0, stream>>>(
        emb_table, mlp_w1, mlp_b1, mlp_w2, mlp_b2, tp_w,
        fc_w1, fc_b1, fc_w2, fc_b2, fc_w3, fc_b3,
        rows_g, B_g, (float4*)table, (int4*)deg, n4, zb, n_atom);

    deg_kernel<<<(n_edges + 255) / 256, 256, 0, stream>>>(edge_dst, deg, n_edges);

    partial_kernel<<<nb, 1024, 0, stream>>>(deg, bsum, n_nodes);

    scan_write_kernel<<<nb, 1024, 0, stream>>>(deg, bsum, starts, cursor,
                                               n_nodes, nb);

    edge_kernel<<<(n_edges + 255) / 256, 256, 0, stream>>>(
        pos, A, batch, edge_src, edge_dst, edge_shifts, cell,
        (const float4*)table, records, cursor, n_edges);

    gather_kernel<<<(n_nodes + 3) / 4, 256, 0, stream>>>(
        records, starts, deg, A, rows_g, B_g, (float*)d_out, n_nodes, n_atom);
}

// Round 10
// 96.709 us; speedup vs baseline: 38.8510x; 1.1665x over previous
//
#include <hip/hip_runtime.h>
#include <hip/hip_fp16.h>
#include <cstddef>

// ICTDIrrepsE3Conv — round 10.
//  - gates = f(edge_length) only -> 8192-entry lerp table
//  - atom-type factorization: rows[10][8], B[10][3][8][16] precomputed
//  - CSR gather, streaming M accumulation + per-atom B finish
//  - NEW: fp16-packed records (8 x half2(G_iq,G8) + asrc, 40B stride)
//    -> record traffic 40MB -> 20MB each way
//  - NEW: rank trick — deg_kernel stores atomicAdd return as rank[e];
//    edge_kernel computes slot = starts[dst] + rank[e], no atomic.
//  NOTE: 44us fillBufferAligned dispatches in the profile are the harness's
//  256MiB poison fills, not ours (round 7->8 A/B).

#define TBL_N 8192
#define TBL_SCALE 1024.0f   // TBL_N / 8.0 range

__device__ __forceinline__ float silu(float x) {
    return x / (1.0f + __expf(-x));
}

__device__ __forceinline__ unsigned pack_half2(float lo, float hi) {
    unsigned a = __half_as_ushort(__float2half_rn(lo));
    unsigned b = __half_as_ushort(__float2half_rn(hi));
    return (b << 16) | a;
}

// ---- fused setup: blocks [0,zb) zero deg; [zb,zb+n_atom) rows+B;
//      [zb+n_atom, ...) table ----
__global__ __launch_bounds__(256) void setup_kernel(
    const float* __restrict__ emb_table,
    const float* __restrict__ w1, const float* __restrict__ b1,
    const float* __restrict__ w2, const float* __restrict__ b2,
    const float* __restrict__ tp_w,
    const float* __restrict__ fc_w1, const float* __restrict__ fc_b1,
    const float* __restrict__ fc_w2, const float* __restrict__ fc_b2,
    const float* __restrict__ fc_w3, const float* __restrict__ fc_b3,
    float* __restrict__ rows_g, float* __restrict__ B_g,
    float4* __restrict__ table,
    int4* __restrict__ deg4, int n4, int zb, int n_atom)
{
    int bid = blockIdx.x;
    int tid = threadIdx.x;

    if (bid < zb) {
        int i = bid * 256 + tid;
        if (i < n4) deg4[i] = make_int4(0, 0, 0, 0);
        return;
    }
    if (bid < zb + n_atom) {
        __shared__ float s_r[8];
        int a = bid - zb;
        if (tid < 8) {
            float e[16];
            #pragma unroll
            for (int i = 0; i < 16; i++) e[i] = emb_table[a * 16 + i];
            float acc_j = b2[tid];
            for (int k = 0; k < 64; k++) {
                float acc = b1[k];
                #pragma unroll
                for (int i = 0; i < 16; i++) acc = fmaf(e[i], w1[i * 64 + k], acc);
                acc_j = fmaf(silu(acc), w2[k * 8 + tid], acc_j);
            }
            s_r[tid] = acc_j;
            rows_g[a * 8 + tid] = acc_j;
        }
        __syncthreads();
        for (int t = tid; t < 384; t += 256) {
            int pp = t >> 7, ub = (t >> 4) & 7, wb = t & 15;
            int P = (pp == 0) ? 0 : (pp == 1) ? 3 : 9;
            float acc = 0.0f;
            #pragma unroll
            for (int v = 0; v < 8; v++)
                acc = fmaf(s_r[v], tp_w[P * 1024 + (ub * 8 + v) * 16 + wb], acc);
            B_g[a * 384 + t] = acc;
        }
        return;
    }

    // table: 4 samples per block, 1 wave per sample
    __shared__ float s_h1[4][64];
    int tb = bid - zb - n_atom;
    int s = tid >> 6;
    int k = tid & 63;
    int samp = tb * 4 + s;
    float len = (float)samp * (1.0f / TBL_SCALE);

    float emb[16];
    const float inv_step = 17.0f / 5.0f;
    #pragma unroll
    for (int b = 0; b < 16; b++) {
        float d = len * inv_step - (float)(b + 1);
        emb[b] = __expf(-d * d) * 3.5714285714285716f; // 4/1.12
    }

    float acc = fc_b1[k];
    #pragma unroll
    for (int b = 0; b < 16; b++) acc = fmaf(emb[b], fc_w1[b * 64 + k], acc);
    s_h1[s][k] = silu(acc);
    __syncthreads();

    float acc2 = fc_b2[k];
    #pragma unroll
    for (int j = 0; j < 64; j++)
        acc2 = fmaf(s_h1[s][j], fc_w2[j * 64 + k], acc2);
    float h2 = silu(acc2);

    float p0 = h2 * fc_w3[k * 15 + 0];
    float p3 = h2 * fc_w3[k * 15 + 3];
    float p9 = h2 * fc_w3[k * 15 + 9];
    #pragma unroll
    for (int off = 32; off > 0; off >>= 1) {
        p0 += __shfl_down(p0, off, 64);
        p3 += __shfl_down(p3, off, 64);
        p9 += __shfl_down(p9, off, 64);
    }
    if (k == 0) {
        table[samp] = make_float4((fc_b3[0] + p0) * 0.125f,
                                  (fc_b3[3] + p3) * 0.125f,
                                  (fc_b3[9] + p9) * 0.125f, 0.0f);
    }
}

// ---- degree histogram + per-edge rank within its dst bucket ----
__global__ __launch_bounds__(256) void deg_kernel(
    const int* __restrict__ edge_dst, int* __restrict__ deg,
    int* __restrict__ rank, int n_edges)
{
    int e = blockIdx.x * blockDim.x + threadIdx.x;
    if (e >= n_edges) return;
    rank[e] = atomicAdd(&deg[edge_dst[e]], 1);
}

__global__ __launch_bounds__(1024) void partial_kernel(
    const int* __restrict__ deg, int* __restrict__ bsum, int n)
{
    __shared__ int red[1024];
    int tid = threadIdx.x;
    int i = blockIdx.x * 1024 + tid;
    red[tid] = (i < n) ? deg[i] : 0;
    __syncthreads();
    #pragma unroll
    for (int off = 512; off > 0; off >>= 1) {
        if (tid < off) red[tid] += red[tid + off];
        __syncthreads();
    }
    if (tid == 0) bsum[blockIdx.x] = red[0];
}

__global__ __launch_bounds__(1024) void scan_write_kernel(
    const int* __restrict__ deg, const int* __restrict__ bsum,
    int* __restrict__ starts, int n, int nb)
{
    __shared__ int s[1024];
    __shared__ int sb[1024];
    int tid = threadIdx.x;

    sb[tid] = (tid < nb) ? bsum[tid] : 0;
    int i = blockIdx.x * 1024 + tid;
    int v = (i < n) ? deg[i] : 0;
    s[tid] = v;
    __syncthreads();
    #pragma unroll
    for (int off = 1; off < 1024; off <<= 1) {
        int t1 = (tid >= off) ? s[tid - off] : 0;
        int t2 = (tid >= off) ? sb[tid - off] : 0;
        __syncthreads();
        s[tid] += t1;
        sb[tid] += t2;
        __syncthreads();
    }
    int base = (blockIdx.x == 0) ? 0 : sb[blockIdx.x - 1];
    if (i < n) starts[i] = base + s[tid] - v;
}

// ---- per-edge: geometry + table-lerp gates + 40B fp16 record ----
// record (10 floats): words 0..7 = half2(G_iq, G8), word 8 = asrc, word 9 pad
__global__ __launch_bounds__(256) void edge_kernel(
    const float* __restrict__ pos,
    const int* __restrict__ A,
    const int* __restrict__ batch,
    const int* __restrict__ edge_src,
    const int* __restrict__ edge_dst,
    const float* __restrict__ edge_shifts,
    const float* __restrict__ cell,
    const float4* __restrict__ table,
    const int* __restrict__ starts,
    const int* __restrict__ rank,
    float* __restrict__ records,
    int n_edges)
{
    int e = blockIdx.x * blockDim.x + threadIdx.x;
    if (e >= n_edges) return;

    int src = edge_src[e];
    int dst = edge_dst[e];

    float sh0 = edge_shifts[3 * (size_t)e + 0];
    float sh1 = edge_shifts[3 * (size_t)e + 1];
    float sh2 = edge_shifts[3 * (size_t)e + 2];
    int g = batch[src];
    const float* C = cell + (size_t)g * 9;
    float shx = sh0 * C[0] + sh1 * C[3] + sh2 * C[6];
    float shy = sh0 * C[1] + sh1 * C[4] + sh2 * C[7];
    float shz = sh0 * C[2] + sh1 * C[5] + sh2 * C[8];

    float vx = pos[3 * (size_t)dst + 0] - pos[3 * (size_t)src + 0] + shx;
    float vy = pos[3 * (size_t)dst + 1] - pos[3 * (size_t)src + 1] + shy;
    float vz = pos[3 * (size_t)dst + 2] - pos[3 * (size_t)src + 2] + shz;

    float len = sqrtf(vx * vx + vy * vy + vz * vz);
    float invl = 1.0f / fmaxf(len, 1e-8f);
    float nx = vx * invl, ny = vy * invl, nz = vz * invl;

    float t = fminf(len * TBL_SCALE, (float)(TBL_N - 1));
    int i0 = (int)t;
    i0 = min(i0, TBL_N - 2);
    float fr = t - (float)i0;
    float4 T0 = table[i0];
    float4 T1 = table[i0 + 1];
    float g0 = fmaf(fr, T1.x - T0.x, T0.x);
    float g1 = fmaf(fr, T1.y - T0.y, T0.y);
    float g2 = fmaf(fr, T1.z - T0.z, T0.z);

    const float s3  = 1.7320508075688772f;
    const float s15 = 3.872983346207417f;
    const float s5  = 2.23606797749979f;
    float G0 = g0;
    float G1 = g1 * s3 * ny, G2 = g1 * s3 * nz, G3 = g1 * s3 * nx;
    float G4 = g2 * s15 * nx * ny;
    float G5 = g2 * s15 * ny * nz;
    float G6 = g2 * 0.5f * s5 * (3.0f * nz * nz - 1.0f);
    float G7 = g2 * s15 * nx * nz;
    float G8 = g2 * 0.5f * s15 * (nx * nx - ny * ny);

    int asrc = A[src];
    int slot = starts[dst] + rank[e];

    unsigned u0 = pack_half2(G0, G8);
    unsigned u1 = pack_half2(G1, G8);
    unsigned u2 = pack_half2(G2, G8);
    unsigned u3 = pack_half2(G3, G8);
    unsigned u4 = pack_half2(G4, G8);
    unsigned u5 = pack_half2(G5, G8);
    unsigned u6 = pack_half2(G6, G8);
    unsigned u7 = pack_half2(G7, G8);

    float2* r2 = (float2*)(records + (size_t)slot * 10);
    r2[0] = make_float2(__uint_as_float(u0), __uint_as_float(u1));
    r2[1] = make_float2(__uint_as_float(u2), __uint_as_float(u3));
    r2[2] = make_float2(__uint_as_float(u4), __uint_as_float(u5));
    r2[3] = make_float2(__uint_as_float(u6), __uint_as_float(u7));
    r2[4] = make_float2(__int_as_float(asrc), 0.0f);
}

// ---- one wave per node: streaming M-accumulate, per-atom B finish ----
__global__ __launch_bounds__(256) void gather_kernel(
    const float* __restrict__ records,
    const int* __restrict__ starts,
    const int* __restrict__ deg,
    const int* __restrict__ A,
    const float* __restrict__ rows_g,
    const float* __restrict__ B_g,
    float* __restrict__ out, int n_nodes, int n_atom)
{
    __shared__ float s_B[3840];      // [a][pp*128 + u*16 + w]
    __shared__ float s_rows[80];     // [a][u]
    __shared__ float s_M[4][80];     // per wave: [i'*8 + u], i' in 0..8

    int tid = threadIdx.x;
    {
        float4* dB = (float4*)s_B;
        const float4* sB = (const float4*)B_g;
        int nB4 = n_atom * 96;
        for (int t = tid; t < nB4; t += 256) dB[t] = sB[t];
        if (tid < n_atom * 8) s_rows[tid] = rows_g[tid];
    }
    __syncthreads();

    int wv = tid >> 6;
    int lane = tid & 63;
    int node = blockIdx.x * 4 + wv;
    if (node >= n_nodes) return;

    int start = starts[node];
    int d = deg[node];
    int iq = lane >> 3, u = lane & 7;
    int anode = A[node];

    // phase 1: streaming M accumulation; 2 dword loads per edge
    float m = 0.0f, m8 = 0.0f;
    const float* recs = records + (size_t)start * 10;
    int j = 0;
    for (; j + 4 <= d; j += 4) {
        const unsigned* r0 = (const unsigned*)(recs + (size_t)(j + 0) * 10);
        const unsigned* r1 = (const unsigned*)(recs + (size_t)(j + 1) * 10);
        const unsigned* r2 = (const unsigned*)(recs + (size_t)(j + 2) * 10);
        const unsigned* r3 = (const unsigned*)(recs + (size_t)(j + 3) * 10);
        unsigned q0 = r0[iq], q1 = r1[iq], q2 = r2[iq], q3 = r3[iq];
        int a0 = (int)r0[8], a1 = (int)r1[8], a2 = (int)r2[8], a3 = (int)r3[8];
        float2 p0 = __half22float2(*reinterpret_cast<const __half2*>(&q0));
        float2 p1 = __half22float2(*reinterpret_cast<const __half2*>(&q1));
        float2 p2 = __half22float2(*reinterpret_cast<const __half2*>(&q2));
        float2 p3 = __half22float2(*reinterpret_cast<const __half2*>(&q3));
        float c0 = s_rows[a0 * 8 + u];
        float c1 = s_rows[a1 * 8 + u];
        float c2 = s_rows[a2 * 8 + u];
        float c3 = s_rows[a3 * 8 + u];
        m  = fmaf(p0.x, c0, m);  m8 = fmaf(p0.y, c0, m8);
        m  = fmaf(p1.x, c1, m);  m8 = fmaf(p1.y, c1, m8);
        m  = fmaf(p2.x, c2, m);  m8 = fmaf(p2.y, c2, m8);
        m  = fmaf(p3.x, c3, m);  m8 = fmaf(p3.y, c3, m8);
    }
    for (; j < d; j++) {
        const unsigned* r0 = (const unsigned*)(recs + (size_t)j * 10);
        unsigned q0 = r0[iq];
        int a0 = (int)r0[8];
        float2 p0 = __half22float2(*reinterpret_cast<const __half2*>(&q0));
        float c0 = s_rows[a0 * 8 + u];
        m  = fmaf(p0.x, c0, m);
        m8 = fmaf(p0.y, c0, m8);
    }
    s_M[wv][iq * 8 + u] = m;
    if (lane < 8) s_M[wv][64 + u] = m8;   // only iq==0 lanes' m8 consumed

    // phase 2: 144 contractions of length 8 against per-atom B
    const float* Bn = s_B + anode * 384;
    float invd = 1.0f / fmaxf((float)d, 1.0f);
    float* row = out + (size_t)node * 144;
    {
        int c = lane;
        int pp, w, ip;
        if (c < 16) { pp = 0; w = c; ip = 0; }
        else { int t = c - 16; pp = 1; w = t / 3; ip = 1 + (t - 3 * (t / 3)); }
        float acc = 0.0f;
        #pragma unroll
        for (int uu = 0; uu < 8; uu++)
            acc = fmaf(Bn[pp * 128 + uu * 16 + w], s_M[wv][ip * 8 + uu], acc);
        row[c] = acc * invd;
    }
    {
        int t = lane;                      // c = 64 + lane
        int w = t / 5; int i = t - 5 * w;
        float acc = 0.0f;
        #pragma unroll
        for (int uu = 0; uu < 8; uu++)
            acc = fmaf(Bn[256 + uu * 16 + w], s_M[wv][(4 + i) * 8 + uu], acc);
        row[64 + lane] = acc * invd;
    }
    if (lane < 16) {
        int t = 64 + lane;                 // c = 128 + lane
        int w = t / 5; int i = t - 5 * w;
        float acc = 0.0f;
        #pragma unroll
        for (int uu = 0; uu < 8; uu++)
            acc = fmaf(Bn[256 + uu * 16 + w], s_M[wv][(4 + i) * 8 + uu], acc);
        row[128 + lane] = acc * invd;
    }
}

extern "C" void kernel_launch(void* const* d_in, const int* in_sizes, int n_in,
                              void* d_out, int out_size, void* d_ws, size_t ws_size,
                              hipStream_t stream)
{
    const float* pos         = (const float*)d_in[0];
    const int*   A           = (const int*)d_in[1];
    const int*   batch       = (const int*)d_in[2];
    const int*   edge_src    = (const int*)d_in[3];
    const int*   edge_dst    = (const int*)d_in[4];
    const float* edge_shifts = (const float*)d_in[5];
    const float* cell        = (const float*)d_in[6];
    const float* emb_table   = (const float*)d_in[7];
    const float* mlp_w1      = (const float*)d_in[8];
    const float* mlp_b1      = (const float*)d_in[9];
    const float* mlp_w2      = (const float*)d_in[10];
    const float* mlp_b2      = (const float*)d_in[11];
    const float* fc_w1       = (const float*)d_in[12];
    const float* fc_b1       = (const float*)d_in[13];
    const float* fc_w2       = (const float*)d_in[14];
    const float* fc_b2       = (const float*)d_in[15];
    const float* fc_w3       = (const float*)d_in[16];
    const float* fc_b3       = (const float*)d_in[17];
    const float* tp_w        = (const float*)d_in[18];

    int n_nodes = in_sizes[1];
    int n_edges = in_sizes[3];
    int n_atom  = in_sizes[7] / 16;
    int nb      = (n_nodes + 1023) / 1024;

    // ws layout
    float* table   = (float*)d_ws;                        // TBL_N*4 floats
    float* rows_g  = table + (size_t)TBL_N * 4;           // 128 (80 used)
    float* B_g     = rows_g + 128;                        // 3840
    int*   deg     = (int*)(B_g + 3840);                  // n_nodes
    int*   starts  = deg + n_nodes;                       // n_nodes
    int*   bsum    = starts + n_nodes;                    // 1024
    int*   rank    = bsum + 1024;                         // n_edges
    float* records = (float*)(rank + n_edges);            // n_edges*10

    int n4 = (n_nodes + 3) / 4;
    int zb = (n4 + 255) / 256;

    setup_kernel<<<zb + n_atom + TBL_N / 4, 256, 0, stream>>>(
        emb_table, mlp_w1, mlp_b1, mlp_w2, mlp_b2, tp_w,
        fc_w1, fc_b1, fc_w2, fc_b2, fc_w3, fc_b3,
        rows_g, B_g, (float4*)table, (int4*)deg, n4, zb, n_atom);

    deg_kernel<<<(n_edges + 255) / 256, 256, 0, stream>>>(
        edge_dst, deg, rank, n_edges);

    partial_kernel<<<nb, 1024, 0, stream>>>(deg, bsum, n_nodes);

    scan_write_kernel<<<nb, 1024, 0, stream>>>(deg, bsum, starts, n_nodes, nb);

    edge_kernel<<<(n_edges + 255) / 256, 256, 0, stream>>>(
        pos, A, batch, edge_src, edge_dst, edge_shifts, cell,
        (const float4*)table, starts, rank, records, n_edges);

    gather_kernel<<<(n_nodes + 3) / 4, 256, 0, stream>>>(
        records, starts, deg, A, rows_g, B_g, (float*)d_out, n_nodes, n_atom);
}